// Round 1
// baseline (16915.729 us; speedup 1.0000x reference)
//
#include <hip/hip_runtime.h>

// Problem constants (from reference)
#define NN 100000
#define NE 3200000
#define HID 256
#define SDIM 128
#define ADIM 64
#define BN_EPS 1e-5f

__device__ __forceinline__ void atomAdd(float* p, float v) {
    unsafeAtomicAdd(p, v);  // native global_atomic_add_f32 on gfx90a+
}

// ---------------- degrees ----------------
__global__ __launch_bounds__(256)
void k_deg(const int* __restrict__ src, const int* __restrict__ dst,
           float* __restrict__ deg_out, float* __restrict__ deg_in, int E) {
    int g = blockIdx.x * 256 + threadIdx.x;
    if (g >= E) return;
    atomAdd(&deg_out[src[g]], 1.0f);
    atomAdd(&deg_in[dst[g]], 1.0f);
}

__global__ __launch_bounds__(256)
void k_dnorm(const float* __restrict__ dego, const float* __restrict__ degi,
             float* __restrict__ dno, float* __restrict__ dni, int N) {
    int i = blockIdx.x * 256 + threadIdx.x;
    if (i >= N) return;
    dno[i] = rsqrtf(fmaxf(dego[i], 1.0f));
    dni[i] = rsqrtf(fmaxf(degi[i], 1.0f));
}

// ---------------- row scale: Y[r,:] = X[r,:] * s[r] ----------------
__global__ __launch_bounds__(256)
void k_rowscale(const float* __restrict__ X, const float* __restrict__ s,
                float* __restrict__ Y, int shift /*log2(F/4)*/, int total4) {
    int idx = blockIdx.x * 256 + threadIdx.x;
    if (idx >= total4) return;
    int row = idx >> shift;
    float sc = s[row];
    float4 v = reinterpret_cast<const float4*>(X)[idx];
    v.x *= sc; v.y *= sc; v.z *= sc; v.w *= sc;
    reinterpret_cast<float4*>(Y)[idx] = v;
}

// ---------------- SpMM: agg[dst[e],:] += m[src[e],:] ----------------
__global__ __launch_bounds__(256)
void k_spmm(const int* __restrict__ src, const int* __restrict__ dst,
            const float* __restrict__ m, float* __restrict__ agg,
            int shift /*log2(F/4)*/, int total) {
    int g = blockIdx.x * 256 + threadIdx.x;
    if (g >= total) return;
    int e = g >> shift;
    int c = g & ((1 << shift) - 1);
    int F = 4 << shift;
    int s = src[e], d = dst[e];
    float4 v = *reinterpret_cast<const float4*>(m + (size_t)s * F + c * 4);
    float* ap = agg + (size_t)d * F + c * 4;
    atomAdd(ap + 0, v.x);
    atomAdd(ap + 1, v.y);
    atomAdd(ap + 2, v.z);
    atomAdd(ap + 3, v.w);
}

// ---------------- GEMM: out[M,256] = (A[M,K] * rs[row]) @ W[K,256] + bias ----------------
template <int K>
__global__ __launch_bounds__(256)
void k_gemm_rs(const float* __restrict__ A, const float* __restrict__ rs,
               const float* __restrict__ W, const float* __restrict__ bias,
               float* __restrict__ out, int M) {
    __shared__ float As[64][33];
    __shared__ float Bs[32][64];
    const int tid = threadIdx.x;
    const int tx = tid & 15, ty = tid >> 4;
    const int row0 = blockIdx.x * 64;
    const int col0 = blockIdx.y * 64;
    float acc[4][4] = {};
    const int lr = tid >> 3;  // 0..31
    const int lc = tid & 7;   // 0..7 float4 chunk within 32 k

    for (int k0 = 0; k0 < K; k0 += 32) {
        // A tile 64x32 (row-scaled)
        #pragma unroll
        for (int h = 0; h < 2; ++h) {
            int rr = lr + 32 * h;
            int row = row0 + rr;
            float4 a = make_float4(0.f, 0.f, 0.f, 0.f);
            float s = 0.f;
            if (row < M) {
                a = *reinterpret_cast<const float4*>(A + (size_t)row * K + k0 + lc * 4);
                s = rs[row];
            }
            As[rr][lc * 4 + 0] = a.x * s;
            As[rr][lc * 4 + 1] = a.y * s;
            As[rr][lc * 4 + 2] = a.z * s;
            As[rr][lc * 4 + 3] = a.w * s;
        }
        // B tile 32x64
        #pragma unroll
        for (int h = 0; h < 2; ++h) {
            int slot = tid + 256 * h;
            int kk = slot >> 4;
            int c4 = slot & 15;
            float4 b = *reinterpret_cast<const float4*>(W + (size_t)(k0 + kk) * HID + col0 + c4 * 4);
            *reinterpret_cast<float4*>(&Bs[kk][c4 * 4]) = b;
        }
        __syncthreads();
        #pragma unroll
        for (int kk = 0; kk < 32; ++kk) {
            float a[4];
            #pragma unroll
            for (int i = 0; i < 4; ++i) a[i] = As[ty * 4 + i][kk];
            float4 bb = *reinterpret_cast<float4*>(&Bs[kk][tx * 4]);
            float b4[4] = {bb.x, bb.y, bb.z, bb.w};
            #pragma unroll
            for (int i = 0; i < 4; ++i)
                #pragma unroll
                for (int j = 0; j < 4; ++j) acc[i][j] = fmaf(a[i], b4[j], acc[i][j]);
        }
        __syncthreads();
    }
    float4 bias4 = *reinterpret_cast<const float4*>(bias + col0 + tx * 4);
    #pragma unroll
    for (int i = 0; i < 4; ++i) {
        int row = row0 + ty * 4 + i;
        if (row < M) {
            float4 o;
            o.x = acc[i][0] + bias4.x;
            o.y = acc[i][1] + bias4.y;
            o.z = acc[i][2] + bias4.z;
            o.w = acc[i][3] + bias4.w;
            *reinterpret_cast<float4*>(out + (size_t)row * HID + col0 + tx * 4) = o;
        }
    }
}

// ---------------- BN column stats: sum, sumsq per column (256 cols) ----------------
__global__ __launch_bounds__(256)
void k_colstats(const float* __restrict__ X, float* __restrict__ stats, int M) {
    int col = threadIdx.x;
    int base = blockIdx.x * 128;
    int lim = min(128, M - base);
    float s = 0.f, s2 = 0.f;
    for (int r = 0; r < lim; ++r) {
        float x = X[(size_t)(base + r) * HID + col];
        s += x;
        s2 += x * x;
    }
    atomAdd(&stats[col], s);
    atomAdd(&stats[HID + col], s2);
}

// ---------------- BN apply + ReLU (in place) ----------------
__global__ __launch_bounds__(256)
void k_bn_relu(float* __restrict__ X, const float* __restrict__ stats,
               const float* __restrict__ gamma, const float* __restrict__ beta,
               int total4) {
    int idx = blockIdx.x * 256 + threadIdx.x;
    if (idx >= total4) return;
    int col0 = (idx & 63) * 4;  // (idx*4) % 256
    float4 x = reinterpret_cast<float4*>(X)[idx];
    float inv_n = 1.0f / (float)NN;
    float y[4] = {x.x, x.y, x.z, x.w};
    #pragma unroll
    for (int j = 0; j < 4; ++j) {
        int c = col0 + j;
        float mean = stats[c] * inv_n;
        float var = stats[HID + c] * inv_n - mean * mean;
        float sc = gamma[c] * rsqrtf(var + BN_EPS);
        float sh = beta[c] - mean * sc;
        float v = fmaf(y[j], sc, sh);
        y[j] = v > 0.f ? v : 0.f;
    }
    reinterpret_cast<float4*>(X)[idx] = make_float4(y[0], y[1], y[2], y[3]);
}

// ---------------- Q head: out = val + adv - mean(adv) ----------------
__global__ __launch_bounds__(256)
void k_qhead(const float* __restrict__ h, const float* __restrict__ Wa,
             const float* __restrict__ ba, const float* __restrict__ Wv,
             const float* __restrict__ bv, float* __restrict__ out, int M) {
    __shared__ float hs[16][256];
    __shared__ float advs[16][64];
    __shared__ float vparts[16][16];
    __shared__ float means[16], vals[16];
    int tid = threadIdx.x;
    int base = blockIdx.x * 16;
    // stage 16 rows of h
    #pragma unroll
    for (int it = 0; it < 4; ++it) {
        int slot = tid + it * 256;  // float4 slots: 16 rows * 64
        int r = slot >> 6;
        int c4 = slot & 63;
        int row = base + r;
        float4 v = make_float4(0.f, 0.f, 0.f, 0.f);
        if (row < M) v = *reinterpret_cast<const float4*>(h + (size_t)row * HID + c4 * 4);
        *reinterpret_cast<float4*>(&hs[r][c4 * 4]) = v;
    }
    __syncthreads();
    int col = tid & 63, rg = tid >> 6;
    float b = ba[col];
    float acc[4] = {b, b, b, b};
    for (int k = 0; k < HID; ++k) {
        float w = Wa[k * ADIM + col];
        #pragma unroll
        for (int i = 0; i < 4; ++i) acc[i] = fmaf(hs[rg * 4 + i][k], w, acc[i]);
    }
    #pragma unroll
    for (int i = 0; i < 4; ++i) advs[rg * 4 + i][col] = acc[i];
    // val partials: row r handled by 16 threads
    int r = tid >> 4, p = tid & 15;
    float vp = 0.f;
    #pragma unroll
    for (int k = 0; k < 16; ++k) vp += hs[r][p * 16 + k] * Wv[p * 16 + k];
    vparts[r][p] = vp;
    __syncthreads();
    if (tid < 16) {
        float s = 0.f;
        #pragma unroll
        for (int c = 0; c < ADIM; ++c) s += advs[tid][c];
        means[tid] = s * (1.0f / ADIM);
        float v = bv[0];
        #pragma unroll
        for (int q = 0; q < 16; ++q) v += vparts[tid][q];
        vals[tid] = v;
    }
    __syncthreads();
    #pragma unroll
    for (int i = 0; i < 4; ++i) {
        int rr = rg * 4 + i;
        int row = base + rr;
        if (row < M) out[(size_t)row * ADIM + col] = vals[rr] + advs[rr][col] - means[rr];
    }
}

extern "C" void kernel_launch(void* const* d_in, const int* in_sizes, int n_in,
                              void* d_out, int out_size, void* d_ws, size_t ws_size,
                              hipStream_t stream) {
    const float* feat = (const float*)d_in[0];
    const int* src = (const int*)d_in[1];
    const int* dst = (const int*)d_in[2];
    const float* W1 = (const float*)d_in[3];
    const float* b1 = (const float*)d_in[4];
    const float* g1 = (const float*)d_in[5];
    const float* be1 = (const float*)d_in[6];
    const float* W2 = (const float*)d_in[7];
    const float* b2 = (const float*)d_in[8];
    const float* g2 = (const float*)d_in[9];
    const float* be2 = (const float*)d_in[10];
    const float* Wa = (const float*)d_in[11];
    const float* ba = (const float*)d_in[12];
    const float* Wv = (const float*)d_in[13];
    const float* bv = (const float*)d_in[14];
    float* out = (float*)d_out;

    float* ws = (float*)d_ws;
    float* deg_out = ws;                  // NN
    float* deg_in  = ws + NN;             // NN
    float* dn_out  = ws + 2 * NN;         // NN
    float* dn_in   = ws + 3 * NN;         // NN
    float* stats   = ws + 4 * NN;         // 512
    float* B1 = ws + 4 * NN + 512;        // NN*256
    float* B2 = B1 + (size_t)NN * HID;    // NN*256
    // total: 400512 + 2*25.6M floats = ~206.4 MB

    // degrees + dnorm
    hipMemsetAsync(deg_out, 0, 2 * NN * sizeof(float), stream);
    k_deg<<<(NE + 255) / 256, 256, 0, stream>>>(src, dst, deg_out, deg_in, NE);
    k_dnorm<<<(NN + 255) / 256, 256, 0, stream>>>(deg_out, deg_in, dn_out, dn_in, NN);

    // ---- layer 1 (F=128) ----
    {
        int total4 = NN * (SDIM / 4);  // 3.2M
        k_rowscale<<<(total4 + 255) / 256, 256, 0, stream>>>(feat, dn_out, B1, 5, total4);
        hipMemsetAsync(B2, 0, (size_t)NN * SDIM * sizeof(float), stream);
        int total = NE * (SDIM / 4);  // 102.4M
        k_spmm<<<(total + 255) / 256, 256, 0, stream>>>(src, dst, B1, B2, 5, total);
        dim3 grid((NN + 63) / 64, HID / 64);
        k_gemm_rs<SDIM><<<grid, 256, 0, stream>>>(B2, dn_in, W1, b1, B1, NN);
        hipMemsetAsync(stats, 0, 512 * sizeof(float), stream);
        k_colstats<<<(NN + 127) / 128, 256, 0, stream>>>(B1, stats, NN);
        int t4 = NN * (HID / 4);
        k_bn_relu<<<(t4 + 255) / 256, 256, 0, stream>>>(B1, stats, g1, be1, t4);
    }

    // ---- layer 2 (F=256) ----
    {
        int total4 = NN * (HID / 4);  // 6.4M
        k_rowscale<<<(total4 + 255) / 256, 256, 0, stream>>>(B1, dn_out, B2, 6, total4);
        hipMemsetAsync(B1, 0, (size_t)NN * HID * sizeof(float), stream);
        int total = NE * (HID / 4);  // 204.8M
        k_spmm<<<(total + 255) / 256, 256, 0, stream>>>(src, dst, B2, B1, 6, total);
        dim3 grid((NN + 63) / 64, HID / 64);
        k_gemm_rs<HID><<<grid, 256, 0, stream>>>(B1, dn_in, W2, b2, B2, NN);
        hipMemsetAsync(stats, 0, 512 * sizeof(float), stream);
        k_colstats<<<(NN + 127) / 128, 256, 0, stream>>>(B2, stats, NN);
        int t4 = NN * (HID / 4);
        k_bn_relu<<<(t4 + 255) / 256, 256, 0, stream>>>(B2, stats, g2, be2, t4);
    }

    // ---- Q head ----
    k_qhead<<<(NN + 15) / 16, 256, 0, stream>>>(B2, Wa, ba, Wv, bv, out, NN);
}

// Round 2
// 2091.613 us; speedup vs baseline: 8.0874x; 8.0874x over previous
//
#include <hip/hip_runtime.h>

#define NN 100000
#define NE 3200000
#define HID 256
#define SDIM 128
#define ADIM 64
#define BN_EPS 1e-5f

__device__ __forceinline__ void atomAdd(float* p, float v) {
    unsafeAtomicAdd(p, v);
}

// ---------------- degrees ----------------
__global__ __launch_bounds__(256)
void k_deg(const int* __restrict__ src, const int* __restrict__ dst,
           float* __restrict__ deg_out, float* __restrict__ deg_in, int E) {
    int g = blockIdx.x * 256 + threadIdx.x;
    if (g >= E) return;
    atomAdd(&deg_out[src[g]], 1.0f);
    atomAdd(&deg_in[dst[g]], 1.0f);
}

__global__ __launch_bounds__(256)
void k_dnorm(const float* __restrict__ dego, const float* __restrict__ degi,
             float* __restrict__ dno, float* __restrict__ dni, int N) {
    int i = blockIdx.x * 256 + threadIdx.x;
    if (i >= N) return;
    dno[i] = rsqrtf(fmaxf(dego[i], 1.0f));
    dni[i] = rsqrtf(fmaxf(degi[i], 1.0f));
}

// ---------------- single-block exclusive scan of in-degrees -> row_ptr, cursor ----------------
__global__ __launch_bounds__(1024)
void k_scan(const float* __restrict__ deg_in_f, int* __restrict__ row_ptr,
            int* __restrict__ cursor, int N) {
    __shared__ int partial[1024];
    const int t = threadIdx.x;
    const int chunk = (N + 1023) / 1024;
    const int lo = t * chunk;
    const int hi = min(lo + chunk, N);
    int s = 0;
    for (int i = lo; i < hi; ++i) s += (int)deg_in_f[i];
    partial[t] = s;
    __syncthreads();
    // Hillis-Steele inclusive scan
    for (int off = 1; off < 1024; off <<= 1) {
        int add = (t >= off) ? partial[t - off] : 0;
        __syncthreads();
        partial[t] += add;
        __syncthreads();
    }
    int run = partial[t] - s;  // exclusive prefix of this thread's chunk
    for (int i = lo; i < hi; ++i) {
        row_ptr[i] = run;
        cursor[i] = run;
        run += (int)deg_in_f[i];
    }
    if (t == 1023) row_ptr[N] = run;  // == E
}

// ---------------- scatter edges into CSR buckets ----------------
__global__ __launch_bounds__(256)
void k_scatter(const int* __restrict__ src, const int* __restrict__ dst,
               int* __restrict__ cursor, int* __restrict__ csr_src, int E) {
    int g = blockIdx.x * 256 + threadIdx.x;
    if (g >= E) return;
    int d = dst[g];
    int pos = atomicAdd(&cursor[d], 1);
    csr_src[pos] = src[g];
}

// ---------------- pull-based SpMM: Y[n,:] = dni[n] * sum_{e in CSR[n]} dno[src_e] * X[src_e,:]
template <int F>
__global__ __launch_bounds__(256)
void k_spmm_csr(const int* __restrict__ row_ptr, const int* __restrict__ csr_src,
                const float* __restrict__ X, const float* __restrict__ dno,
                const float* __restrict__ dni, float* __restrict__ Y, int N) {
    const int node = blockIdx.x * 4 + (threadIdx.x >> 6);
    if (node >= N) return;
    const int lane = threadIdx.x & 63;
    const int beg = row_ptr[node];
    const int end = row_ptr[node + 1];
    float4 acc = make_float4(0.f, 0.f, 0.f, 0.f);

    if (F == 256) {
        const float* Xl = X + lane * 4;
        int e = beg;
        for (; e + 1 < end; e += 2) {
            int s0 = csr_src[e];
            int s1 = csr_src[e + 1];
            float w0 = dno[s0];
            float w1 = dno[s1];
            float4 v0 = *reinterpret_cast<const float4*>(Xl + (size_t)s0 * 256);
            float4 v1 = *reinterpret_cast<const float4*>(Xl + (size_t)s1 * 256);
            acc.x = fmaf(v0.x, w0, acc.x); acc.y = fmaf(v0.y, w0, acc.y);
            acc.z = fmaf(v0.z, w0, acc.z); acc.w = fmaf(v0.w, w0, acc.w);
            acc.x = fmaf(v1.x, w1, acc.x); acc.y = fmaf(v1.y, w1, acc.y);
            acc.z = fmaf(v1.z, w1, acc.z); acc.w = fmaf(v1.w, w1, acc.w);
        }
        if (e < end) {
            int s0 = csr_src[e];
            float w0 = dno[s0];
            float4 v0 = *reinterpret_cast<const float4*>(Xl + (size_t)s0 * 256);
            acc.x = fmaf(v0.x, w0, acc.x); acc.y = fmaf(v0.y, w0, acc.y);
            acc.z = fmaf(v0.z, w0, acc.z); acc.w = fmaf(v0.w, w0, acc.w);
        }
        float wi = dni[node];
        float4 o = make_float4(acc.x * wi, acc.y * wi, acc.z * wi, acc.w * wi);
        *reinterpret_cast<float4*>(Y + (size_t)node * 256 + lane * 4) = o;
    } else {
        // F == 128: two edges in flight, half-wave each, lanes hold float4
        const int half = lane >> 5;
        const int l = lane & 31;
        const float* Xl = X + l * 4;
        for (int e = beg + half; e < end; e += 2) {
            int s = csr_src[e];
            float w = dno[s];
            float4 v = *reinterpret_cast<const float4*>(Xl + (size_t)s * 128);
            acc.x = fmaf(v.x, w, acc.x); acc.y = fmaf(v.y, w, acc.y);
            acc.z = fmaf(v.z, w, acc.z); acc.w = fmaf(v.w, w, acc.w);
        }
        acc.x += __shfl_xor(acc.x, 32);
        acc.y += __shfl_xor(acc.y, 32);
        acc.z += __shfl_xor(acc.z, 32);
        acc.w += __shfl_xor(acc.w, 32);
        if (half == 0) {
            float wi = dni[node];
            float4 o = make_float4(acc.x * wi, acc.y * wi, acc.z * wi, acc.w * wi);
            *reinterpret_cast<float4*>(Y + (size_t)node * 128 + l * 4) = o;
        }
    }
}

// ---------------- GEMM: out[M,256] = A[M,K] @ W[K,256] + bias ----------------
template <int K>
__global__ __launch_bounds__(256)
void k_gemm(const float* __restrict__ A, const float* __restrict__ W,
            const float* __restrict__ bias, float* __restrict__ out, int M) {
    __shared__ float As[64][33];
    __shared__ float Bs[32][64];
    const int tid = threadIdx.x;
    const int tx = tid & 15, ty = tid >> 4;
    const int row0 = blockIdx.x * 64;
    const int col0 = blockIdx.y * 64;
    float acc[4][4] = {};
    const int lr = tid >> 3;
    const int lc = tid & 7;

    for (int k0 = 0; k0 < K; k0 += 32) {
        #pragma unroll
        for (int h = 0; h < 2; ++h) {
            int rr = lr + 32 * h;
            int row = row0 + rr;
            float4 a = make_float4(0.f, 0.f, 0.f, 0.f);
            if (row < M) a = *reinterpret_cast<const float4*>(A + (size_t)row * K + k0 + lc * 4);
            As[rr][lc * 4 + 0] = a.x;
            As[rr][lc * 4 + 1] = a.y;
            As[rr][lc * 4 + 2] = a.z;
            As[rr][lc * 4 + 3] = a.w;
        }
        #pragma unroll
        for (int h = 0; h < 2; ++h) {
            int slot = tid + 256 * h;
            int kk = slot >> 4;
            int c4 = slot & 15;
            float4 b = *reinterpret_cast<const float4*>(W + (size_t)(k0 + kk) * HID + col0 + c4 * 4);
            *reinterpret_cast<float4*>(&Bs[kk][c4 * 4]) = b;
        }
        __syncthreads();
        #pragma unroll
        for (int kk = 0; kk < 32; ++kk) {
            float a[4];
            #pragma unroll
            for (int i = 0; i < 4; ++i) a[i] = As[ty * 4 + i][kk];
            float4 bb = *reinterpret_cast<float4*>(&Bs[kk][tx * 4]);
            float b4[4] = {bb.x, bb.y, bb.z, bb.w};
            #pragma unroll
            for (int i = 0; i < 4; ++i)
                #pragma unroll
                for (int j = 0; j < 4; ++j) acc[i][j] = fmaf(a[i], b4[j], acc[i][j]);
        }
        __syncthreads();
    }
    float4 bias4 = *reinterpret_cast<const float4*>(bias + col0 + tx * 4);
    #pragma unroll
    for (int i = 0; i < 4; ++i) {
        int row = row0 + ty * 4 + i;
        if (row < M) {
            float4 o;
            o.x = acc[i][0] + bias4.x;
            o.y = acc[i][1] + bias4.y;
            o.z = acc[i][2] + bias4.z;
            o.w = acc[i][3] + bias4.w;
            *reinterpret_cast<float4*>(out + (size_t)row * HID + col0 + tx * 4) = o;
        }
    }
}

// ---------------- BN column stats ----------------
__global__ __launch_bounds__(256)
void k_colstats(const float* __restrict__ X, float* __restrict__ stats, int M) {
    int col = threadIdx.x;
    int base = blockIdx.x * 128;
    int lim = min(128, M - base);
    float s = 0.f, s2 = 0.f;
    for (int r = 0; r < lim; ++r) {
        float x = X[(size_t)(base + r) * HID + col];
        s += x;
        s2 += x * x;
    }
    atomAdd(&stats[col], s);
    atomAdd(&stats[HID + col], s2);
}

// ---------------- BN apply + ReLU (in place) ----------------
__global__ __launch_bounds__(256)
void k_bn_relu(float* __restrict__ X, const float* __restrict__ stats,
               const float* __restrict__ gamma, const float* __restrict__ beta,
               int total4) {
    int idx = blockIdx.x * 256 + threadIdx.x;
    if (idx >= total4) return;
    int col0 = (idx & 63) * 4;
    float4 x = reinterpret_cast<float4*>(X)[idx];
    float inv_n = 1.0f / (float)NN;
    float y[4] = {x.x, x.y, x.z, x.w};
    #pragma unroll
    for (int j = 0; j < 4; ++j) {
        int c = col0 + j;
        float mean = stats[c] * inv_n;
        float var = stats[HID + c] * inv_n - mean * mean;
        float sc = gamma[c] * rsqrtf(var + BN_EPS);
        float sh = beta[c] - mean * sc;
        float v = fmaf(y[j], sc, sh);
        y[j] = v > 0.f ? v : 0.f;
    }
    reinterpret_cast<float4*>(X)[idx] = make_float4(y[0], y[1], y[2], y[3]);
}

// ---------------- Q head ----------------
__global__ __launch_bounds__(256)
void k_qhead(const float* __restrict__ h, const float* __restrict__ Wa,
             const float* __restrict__ ba, const float* __restrict__ Wv,
             const float* __restrict__ bv, float* __restrict__ out, int M) {
    __shared__ float hs[16][256];
    __shared__ float advs[16][64];
    __shared__ float vparts[16][16];
    __shared__ float means[16], vals[16];
    int tid = threadIdx.x;
    int base = blockIdx.x * 16;
    #pragma unroll
    for (int it = 0; it < 4; ++it) {
        int slot = tid + it * 256;
        int r = slot >> 6;
        int c4 = slot & 63;
        int row = base + r;
        float4 v = make_float4(0.f, 0.f, 0.f, 0.f);
        if (row < M) v = *reinterpret_cast<const float4*>(h + (size_t)row * HID + c4 * 4);
        *reinterpret_cast<float4*>(&hs[r][c4 * 4]) = v;
    }
    __syncthreads();
    int col = tid & 63, rg = tid >> 6;
    float b = ba[col];
    float acc[4] = {b, b, b, b};
    for (int k = 0; k < HID; ++k) {
        float w = Wa[k * ADIM + col];
        #pragma unroll
        for (int i = 0; i < 4; ++i) acc[i] = fmaf(hs[rg * 4 + i][k], w, acc[i]);
    }
    #pragma unroll
    for (int i = 0; i < 4; ++i) advs[rg * 4 + i][col] = acc[i];
    int r = tid >> 4, p = tid & 15;
    float vp = 0.f;
    #pragma unroll
    for (int k = 0; k < 16; ++k) vp += hs[r][p * 16 + k] * Wv[p * 16 + k];
    vparts[r][p] = vp;
    __syncthreads();
    if (tid < 16) {
        float s = 0.f;
        #pragma unroll
        for (int c = 0; c < ADIM; ++c) s += advs[tid][c];
        means[tid] = s * (1.0f / ADIM);
        float v = bv[0];
        #pragma unroll
        for (int q = 0; q < 16; ++q) v += vparts[tid][q];
        vals[tid] = v;
    }
    __syncthreads();
    #pragma unroll
    for (int i = 0; i < 4; ++i) {
        int rr = rg * 4 + i;
        int row = base + rr;
        if (row < M) out[(size_t)row * ADIM + col] = vals[rr] + advs[rr][col] - means[rr];
    }
}

extern "C" void kernel_launch(void* const* d_in, const int* in_sizes, int n_in,
                              void* d_out, int out_size, void* d_ws, size_t ws_size,
                              hipStream_t stream) {
    const float* feat = (const float*)d_in[0];
    const int* src = (const int*)d_in[1];
    const int* dst = (const int*)d_in[2];
    const float* W1 = (const float*)d_in[3];
    const float* b1 = (const float*)d_in[4];
    const float* g1 = (const float*)d_in[5];
    const float* be1 = (const float*)d_in[6];
    const float* W2 = (const float*)d_in[7];
    const float* b2 = (const float*)d_in[8];
    const float* g2 = (const float*)d_in[9];
    const float* be2 = (const float*)d_in[10];
    const float* Wa = (const float*)d_in[11];
    const float* ba = (const float*)d_in[12];
    const float* Wv = (const float*)d_in[13];
    const float* bv = (const float*)d_in[14];
    float* out = (float*)d_out;

    float* ws = (float*)d_ws;
    // layout (4-byte units, all 16B aligned):
    float* deg_out = ws;                         // NN
    float* deg_in  = ws + NN;                    // NN
    float* dn_out  = ws + 2 * NN;                // NN
    float* dn_in   = ws + 3 * NN;                // NN
    float* stats   = ws + 4 * NN;                // 512
    int* row_ptr   = (int*)(ws + 4 * NN + 512);  // NN+1 (padded to NN+4)
    int* cursor    = row_ptr + NN + 4;           // NN
    int* csr_src   = cursor + NN;                // NE
    float* B1 = (float*)(csr_src + NE);          // NN*256
    float* B2 = B1 + (size_t)NN * HID;           // NN*256
    // total ~220 MB

    // degrees + dnorm + CSR build
    hipMemsetAsync(deg_out, 0, 2 * NN * sizeof(float), stream);
    k_deg<<<(NE + 255) / 256, 256, 0, stream>>>(src, dst, deg_out, deg_in, NE);
    k_dnorm<<<(NN + 255) / 256, 256, 0, stream>>>(deg_out, deg_in, dn_out, dn_in, NN);
    k_scan<<<1, 1024, 0, stream>>>(deg_in, row_ptr, cursor, NN);
    k_scatter<<<(NE + 255) / 256, 256, 0, stream>>>(src, dst, cursor, csr_src, NE);

    // ---- layer 1 (F=128) ----
    k_spmm_csr<SDIM><<<(NN + 3) / 4, 256, 0, stream>>>(row_ptr, csr_src, feat, dn_out, dn_in, B1, NN);
    {
        dim3 grid((NN + 63) / 64, HID / 64);
        k_gemm<SDIM><<<grid, 256, 0, stream>>>(B1, W1, b1, B2, NN);
        hipMemsetAsync(stats, 0, 512 * sizeof(float), stream);
        k_colstats<<<(NN + 127) / 128, 256, 0, stream>>>(B2, stats, NN);
        int t4 = NN * (HID / 4);
        k_bn_relu<<<(t4 + 255) / 256, 256, 0, stream>>>(B2, stats, g1, be1, t4);
    }

    // ---- layer 2 (F=256) ----
    k_spmm_csr<HID><<<(NN + 3) / 4, 256, 0, stream>>>(row_ptr, csr_src, B2, dn_out, dn_in, B1, NN);
    {
        dim3 grid((NN + 63) / 64, HID / 64);
        k_gemm<HID><<<grid, 256, 0, stream>>>(B1, W2, b2, B2, NN);
        hipMemsetAsync(stats, 0, 512 * sizeof(float), stream);
        k_colstats<<<(NN + 127) / 128, 256, 0, stream>>>(B2, stats, NN);
        int t4 = NN * (HID / 4);
        k_bn_relu<<<(t4 + 255) / 256, 256, 0, stream>>>(B2, stats, g2, be2, t4);
    }

    // ---- Q head ----
    k_qhead<<<(NN + 15) / 16, 256, 0, stream>>>(B2, Wa, ba, Wv, bv, out, NN);
}

// Round 3
// 1676.102 us; speedup vs baseline: 10.0923x; 1.2479x over previous
//
#include <hip/hip_runtime.h>
#include <hip/hip_bf16.h>

#define NN 100000
#define NE 3200000
#define HID 256
#define SDIM 128
#define ADIM 64
#define BN_EPS 1e-5f

typedef __attribute__((ext_vector_type(8))) short short8;
typedef __attribute__((ext_vector_type(4))) float f32x4;

__device__ __forceinline__ void atomAdd(float* p, float v) { unsafeAtomicAdd(p, v); }
__device__ __forceinline__ float bf2f(ushort u) {
    union { unsigned i; float f; } c; c.i = ((unsigned)u) << 16; return c.f;
}
__device__ __forceinline__ ushort f2bf(float x) {
    __hip_bfloat16 h = __float2bfloat16(x);
    return *reinterpret_cast<ushort*>(&h);
}

// ---------------- degrees ----------------
__global__ __launch_bounds__(256)
void k_deg(const int* __restrict__ src, const int* __restrict__ dst,
           float* __restrict__ deg_out, float* __restrict__ deg_in, int E) {
    int g = blockIdx.x * 256 + threadIdx.x;
    if (g >= E) return;
    atomAdd(&deg_out[src[g]], 1.0f);
    atomAdd(&deg_in[dst[g]], 1.0f);
}

__global__ __launch_bounds__(256)
void k_dnorm(const float* __restrict__ dego, const float* __restrict__ degi,
             float* __restrict__ dno, float* __restrict__ dni, int N) {
    int i = blockIdx.x * 256 + threadIdx.x;
    if (i >= N) return;
    dno[i] = rsqrtf(fmaxf(dego[i], 1.0f));
    dni[i] = rsqrtf(fmaxf(degi[i], 1.0f));
}

// ---------------- single-block scan -> row_ptr, cursor ----------------
__global__ __launch_bounds__(1024)
void k_scan(const float* __restrict__ deg_in_f, int* __restrict__ row_ptr,
            int* __restrict__ cursor, int N) {
    __shared__ int partial[1024];
    const int t = threadIdx.x;
    const int chunk = (N + 1023) / 1024;
    const int lo = t * chunk;
    const int hi = min(lo + chunk, N);
    int s = 0;
    for (int i = lo; i < hi; ++i) s += (int)deg_in_f[i];
    partial[t] = s;
    __syncthreads();
    for (int off = 1; off < 1024; off <<= 1) {
        int add = (t >= off) ? partial[t - off] : 0;
        __syncthreads();
        partial[t] += add;
        __syncthreads();
    }
    int run = partial[t] - s;
    for (int i = lo; i < hi; ++i) {
        row_ptr[i] = run;
        cursor[i] = run;
        run += (int)deg_in_f[i];
    }
    if (t == 1023) row_ptr[N] = run;
}

// ---------------- scatter edges into CSR ----------------
__global__ __launch_bounds__(256)
void k_scatter(const int* __restrict__ src, const int* __restrict__ dst,
               int* __restrict__ cursor, int* __restrict__ csr_src, int E) {
    int g = blockIdx.x * 256 + threadIdx.x;
    if (g >= E) return;
    int d = dst[g];
    int pos = atomicAdd(&cursor[d], 1);
    csr_src[pos] = src[g];
}

// ---------------- W[K,N] fp32 -> Wt[N,K] bf16 ----------------
__global__ __launch_bounds__(256)
void k_wt(const float* __restrict__ W, ushort* __restrict__ Wt, int K, int N) {
    int idx = blockIdx.x * 256 + threadIdx.x;
    if (idx >= K * N) return;
    int n = idx / K, k = idx - n * K;
    Wt[idx] = f2bf(W[(size_t)k * N + n]);
}

// ---------------- feat fp32 -> bf16 prescaled by dno[row] (F=128) ----------------
__global__ __launch_bounds__(256)
void k_prescale_cvt(const float* __restrict__ X, const float* __restrict__ dno,
                    ushort* __restrict__ Y, int total4) {
    int idx = blockIdx.x * 256 + threadIdx.x;
    if (idx >= total4) return;
    int row = idx >> 5;  // 128/4 = 32 chunks per row
    float s = dno[row];
    float4 v = reinterpret_cast<const float4*>(X)[idx];
    ushort4 o;
    o.x = f2bf(v.x * s); o.y = f2bf(v.y * s);
    o.z = f2bf(v.z * s); o.w = f2bf(v.w * s);
    reinterpret_cast<ushort4*>(Y)[idx] = o;
}

// ---------------- pull SpMM over bf16 rows: Y[n,:] = bf16(dni[n] * sum X[src,:]) ----------------
template <int F>
__global__ __launch_bounds__(256)
void k_spmm_bf16(const int* __restrict__ row_ptr, const int* __restrict__ csr_src,
                 const ushort* __restrict__ X, const float* __restrict__ dni,
                 ushort* __restrict__ Y, int N) {
    const int node = blockIdx.x * 4 + (threadIdx.x >> 6);
    if (node >= N) return;
    const int lane = threadIdx.x & 63;
    const int beg = row_ptr[node];
    const int end = row_ptr[node + 1];
    float acc[4] = {0.f, 0.f, 0.f, 0.f};

    if (F == 256) {
        const ushort* Xl = X + lane * 4;
        int e = beg;
        for (; e + 1 < end; e += 2) {
            int s0 = csr_src[e];
            int s1 = csr_src[e + 1];
            ushort4 v0 = *reinterpret_cast<const ushort4*>(Xl + (size_t)s0 * 256);
            ushort4 v1 = *reinterpret_cast<const ushort4*>(Xl + (size_t)s1 * 256);
            acc[0] += bf2f(v0.x) + bf2f(v1.x);
            acc[1] += bf2f(v0.y) + bf2f(v1.y);
            acc[2] += bf2f(v0.z) + bf2f(v1.z);
            acc[3] += bf2f(v0.w) + bf2f(v1.w);
        }
        if (e < end) {
            int s0 = csr_src[e];
            ushort4 v0 = *reinterpret_cast<const ushort4*>(Xl + (size_t)s0 * 256);
            acc[0] += bf2f(v0.x); acc[1] += bf2f(v0.y);
            acc[2] += bf2f(v0.z); acc[3] += bf2f(v0.w);
        }
        float wi = dni[node];
        ushort4 o;
        o.x = f2bf(acc[0] * wi); o.y = f2bf(acc[1] * wi);
        o.z = f2bf(acc[2] * wi); o.w = f2bf(acc[3] * wi);
        *reinterpret_cast<ushort4*>(Y + (size_t)node * 256 + lane * 4) = o;
    } else {
        // F == 128: two edges in flight, half-wave each
        const int half = lane >> 5;
        const int l = lane & 31;
        const ushort* Xl = X + l * 4;
        for (int e = beg + half; e < end; e += 2) {
            int s = csr_src[e];
            ushort4 v = *reinterpret_cast<const ushort4*>(Xl + (size_t)s * 128);
            acc[0] += bf2f(v.x); acc[1] += bf2f(v.y);
            acc[2] += bf2f(v.z); acc[3] += bf2f(v.w);
        }
        acc[0] += __shfl_xor(acc[0], 32);
        acc[1] += __shfl_xor(acc[1], 32);
        acc[2] += __shfl_xor(acc[2], 32);
        acc[3] += __shfl_xor(acc[3], 32);
        if (half == 0) {
            float wi = dni[node];
            ushort4 o;
            o.x = f2bf(acc[0] * wi); o.y = f2bf(acc[1] * wi);
            o.z = f2bf(acc[2] * wi); o.w = f2bf(acc[3] * wi);
            *reinterpret_cast<ushort4*>(Y + (size_t)node * 128 + l * 4) = o;
        }
    }
}

// ---------------- MFMA GEMM: out[M,256] = A[M,K]bf16 @ Wt[256,K]bf16^T + bias ----------------
// 128x64 tile, 4 waves (each 32 rows x 64 cols), 16x16x32 bf16 MFMA.
template <int K>
__global__ __launch_bounds__(256)
void k_gemm_mfma(const ushort* __restrict__ A, const ushort* __restrict__ Wt,
                 const float* __restrict__ bias, float* __restrict__ out, int M) {
    __shared__ ushort As[128][40];  // 32 k + pad 8
    __shared__ ushort Bs[64][40];
    const int tid = threadIdx.x;
    const int w = tid >> 6;
    const int lane = tid & 63;
    const int row0 = blockIdx.x * 128;
    const int col0 = blockIdx.y * 64;
    f32x4 acc[2][4] = {};

    const int arow = lane & 15;
    const int ak = (lane >> 4) * 8;

    for (int k0 = 0; k0 < K; k0 += 32) {
        // A tile: 128 x 32, two passes of 256 threads x 16B
        #pragma unroll
        for (int h = 0; h < 2; ++h) {
            int r = (tid >> 2) + 64 * h;
            int kk = (tid & 3) * 8;
            int row = row0 + r;
            int4 v = make_int4(0, 0, 0, 0);
            if (row < M) v = *reinterpret_cast<const int4*>(A + (size_t)row * K + k0 + kk);
            *reinterpret_cast<int4*>(&As[r][kk]) = v;
        }
        // B tile: 64 x 32 from Wt[N][K]
        {
            int n = tid >> 2;
            int kk = (tid & 3) * 8;
            int4 v = *reinterpret_cast<const int4*>(Wt + (size_t)(col0 + n) * K + k0 + kk);
            *reinterpret_cast<int4*>(&Bs[n][kk]) = v;
        }
        __syncthreads();

        short8 afr[2], bfr[4];
        #pragma unroll
        for (int mi = 0; mi < 2; ++mi)
            afr[mi] = *reinterpret_cast<const short8*>(&As[w * 32 + mi * 16 + arow][ak]);
        #pragma unroll
        for (int ni = 0; ni < 4; ++ni)
            bfr[ni] = *reinterpret_cast<const short8*>(&Bs[ni * 16 + arow][ak]);
        #pragma unroll
        for (int mi = 0; mi < 2; ++mi)
            #pragma unroll
            for (int ni = 0; ni < 4; ++ni)
                acc[mi][ni] = __builtin_amdgcn_mfma_f32_16x16x32_bf16(afr[mi], bfr[ni], acc[mi][ni], 0, 0, 0);
        __syncthreads();
    }

    // epilogue: D mapping col=lane&15, row=(lane>>4)*4+reg
    const int ncol = lane & 15;
    const int rbase = (lane >> 4) * 4;
    #pragma unroll
    for (int mi = 0; mi < 2; ++mi) {
        #pragma unroll
        for (int ni = 0; ni < 4; ++ni) {
            int col = col0 + ni * 16 + ncol;
            float b = bias[col];
            #pragma unroll
            for (int q = 0; q < 4; ++q) {
                int row = row0 + w * 32 + mi * 16 + rbase + q;
                if (row < M) out[(size_t)row * HID + col] = acc[mi][ni][q] + b;
            }
        }
    }
}

// ---------------- BN column stats ----------------
__global__ __launch_bounds__(256)
void k_colstats(const float* __restrict__ X, float* __restrict__ stats, int M) {
    int col = threadIdx.x;
    int base = blockIdx.x * 128;
    int lim = min(128, M - base);
    float s = 0.f, s2 = 0.f;
    for (int r = 0; r < lim; ++r) {
        float x = X[(size_t)(base + r) * HID + col];
        s += x;
        s2 += x * x;
    }
    atomAdd(&stats[col], s);
    atomAdd(&stats[HID + col], s2);
}

// ---------------- BN + ReLU + dno-prescale -> bf16 (layer-1 output path) ----------------
__global__ __launch_bounds__(256)
void k_bn_relu_ps(const float* __restrict__ X, const float* __restrict__ stats,
                  const float* __restrict__ gamma, const float* __restrict__ beta,
                  const float* __restrict__ dno, ushort* __restrict__ Y, int total4) {
    int idx = blockIdx.x * 256 + threadIdx.x;
    if (idx >= total4) return;
    int row = idx >> 6;
    int col0 = (idx & 63) * 4;
    float4 x = reinterpret_cast<const float4*>(X)[idx];
    float inv_n = 1.0f / (float)NN;
    float s = dno[row];
    float y[4] = {x.x, x.y, x.z, x.w};
    ushort4 o;
    ushort* op = &o.x;
    #pragma unroll
    for (int j = 0; j < 4; ++j) {
        int c = col0 + j;
        float mean = stats[c] * inv_n;
        float var = stats[HID + c] * inv_n - mean * mean;
        float sc = gamma[c] * rsqrtf(var + BN_EPS);
        float sh = beta[c] - mean * sc;
        float v = fmaf(y[j], sc, sh);
        v = v > 0.f ? v : 0.f;
        op[j] = f2bf(v * s);
    }
    reinterpret_cast<ushort4*>(Y)[idx] = o;
}

// ---------------- BN + ReLU in-place fp32 (layer-2, feeds qhead) ----------------
__global__ __launch_bounds__(256)
void k_bn_relu(float* __restrict__ X, const float* __restrict__ stats,
               const float* __restrict__ gamma, const float* __restrict__ beta,
               int total4) {
    int idx = blockIdx.x * 256 + threadIdx.x;
    if (idx >= total4) return;
    int col0 = (idx & 63) * 4;
    float4 x = reinterpret_cast<float4*>(X)[idx];
    float inv_n = 1.0f / (float)NN;
    float y[4] = {x.x, x.y, x.z, x.w};
    #pragma unroll
    for (int j = 0; j < 4; ++j) {
        int c = col0 + j;
        float mean = stats[c] * inv_n;
        float var = stats[HID + c] * inv_n - mean * mean;
        float sc = gamma[c] * rsqrtf(var + BN_EPS);
        float sh = beta[c] - mean * sc;
        float v = fmaf(y[j], sc, sh);
        y[j] = v > 0.f ? v : 0.f;
    }
    reinterpret_cast<float4*>(X)[idx] = make_float4(y[0], y[1], y[2], y[3]);
}

// ---------------- Q head ----------------
__global__ __launch_bounds__(256)
void k_qhead(const float* __restrict__ h, const float* __restrict__ Wa,
             const float* __restrict__ ba, const float* __restrict__ Wv,
             const float* __restrict__ bv, float* __restrict__ out, int M) {
    __shared__ float hs[16][256];
    __shared__ float advs[16][64];
    __shared__ float vparts[16][16];
    __shared__ float means[16], vals[16];
    int tid = threadIdx.x;
    int base = blockIdx.x * 16;
    #pragma unroll
    for (int it = 0; it < 4; ++it) {
        int slot = tid + it * 256;
        int r = slot >> 6;
        int c4 = slot & 63;
        int row = base + r;
        float4 v = make_float4(0.f, 0.f, 0.f, 0.f);
        if (row < M) v = *reinterpret_cast<const float4*>(h + (size_t)row * HID + c4 * 4);
        *reinterpret_cast<float4*>(&hs[r][c4 * 4]) = v;
    }
    __syncthreads();
    int col = tid & 63, rg = tid >> 6;
    float b = ba[col];
    float acc[4] = {b, b, b, b};
    for (int k = 0; k < HID; ++k) {
        float w = Wa[k * ADIM + col];
        #pragma unroll
        for (int i = 0; i < 4; ++i) acc[i] = fmaf(hs[rg * 4 + i][k], w, acc[i]);
    }
    #pragma unroll
    for (int i = 0; i < 4; ++i) advs[rg * 4 + i][col] = acc[i];
    int r = tid >> 4, p = tid & 15;
    float vp = 0.f;
    #pragma unroll
    for (int k = 0; k < 16; ++k) vp += hs[r][p * 16 + k] * Wv[p * 16 + k];
    vparts[r][p] = vp;
    __syncthreads();
    if (tid < 16) {
        float s = 0.f;
        #pragma unroll
        for (int c = 0; c < ADIM; ++c) s += advs[tid][c];
        means[tid] = s * (1.0f / ADIM);
        float v = bv[0];
        #pragma unroll
        for (int q = 0; q < 16; ++q) v += vparts[tid][q];
        vals[tid] = v;
    }
    __syncthreads();
    #pragma unroll
    for (int i = 0; i < 4; ++i) {
        int rr = rg * 4 + i;
        int row = base + rr;
        if (row < M) out[(size_t)row * ADIM + col] = vals[rr] + advs[rr][col] - means[rr];
    }
}

extern "C" void kernel_launch(void* const* d_in, const int* in_sizes, int n_in,
                              void* d_out, int out_size, void* d_ws, size_t ws_size,
                              hipStream_t stream) {
    const float* feat = (const float*)d_in[0];
    const int* src = (const int*)d_in[1];
    const int* dst = (const int*)d_in[2];
    const float* W1 = (const float*)d_in[3];
    const float* b1 = (const float*)d_in[4];
    const float* g1 = (const float*)d_in[5];
    const float* be1 = (const float*)d_in[6];
    const float* W2 = (const float*)d_in[7];
    const float* b2 = (const float*)d_in[8];
    const float* g2 = (const float*)d_in[9];
    const float* be2 = (const float*)d_in[10];
    const float* Wa = (const float*)d_in[11];
    const float* ba = (const float*)d_in[12];
    const float* Wv = (const float*)d_in[13];
    const float* bv = (const float*)d_in[14];
    float* out = (float*)d_out;

    float* ws = (float*)d_ws;
    float* deg_out = ws;                         // NN
    float* deg_in  = ws + NN;                    // NN
    float* dn_out  = ws + 2 * NN;                // NN
    float* dn_in   = ws + 3 * NN;                // NN
    float* stats   = ws + 4 * NN;                // 512
    int* row_ptr   = (int*)(ws + 4 * NN + 512);  // NN+4
    int* cursor    = row_ptr + NN + 4;           // NN
    int* csr_src   = cursor + NN;                // NE
    ushort* Xb = (ushort*)(csr_src + NE);        // NN*256 bf16 (51.2 MB)
    ushort* Ab = Xb + (size_t)NN * HID;          // NN*256 bf16 (51.2 MB)
    float* G   = (float*)(Ab + (size_t)NN * HID); // NN*256 fp32 (102.4 MB)
    ushort* Wt1 = (ushort*)(G + (size_t)NN * HID); // 256*128
    ushort* Wt2 = Wt1 + HID * SDIM;                // 256*256
    // total ~220 MB

    // degrees + dnorm + CSR
    hipMemsetAsync(deg_out, 0, 2 * NN * sizeof(float), stream);
    k_deg<<<(NE + 255) / 256, 256, 0, stream>>>(src, dst, deg_out, deg_in, NE);
    k_dnorm<<<(NN + 255) / 256, 256, 0, stream>>>(deg_out, deg_in, dn_out, dn_in, NN);
    k_scan<<<1, 1024, 0, stream>>>(deg_in, row_ptr, cursor, NN);
    k_scatter<<<(NE + 255) / 256, 256, 0, stream>>>(src, dst, cursor, csr_src, NE);

    // weights -> bf16 transposed
    k_wt<<<(SDIM * HID + 255) / 256, 256, 0, stream>>>(W1, Wt1, SDIM, HID);
    k_wt<<<(HID * HID + 255) / 256, 256, 0, stream>>>(W2, Wt2, HID, HID);

    // ---- layer 1 ----
    {
        int t4 = NN * (SDIM / 4);
        k_prescale_cvt<<<(t4 + 255) / 256, 256, 0, stream>>>(feat, dn_out, Xb, t4);
        k_spmm_bf16<SDIM><<<(NN + 3) / 4, 256, 0, stream>>>(row_ptr, csr_src, Xb, dn_in, Ab, NN);
        dim3 grid((NN + 127) / 128, HID / 64);
        k_gemm_mfma<SDIM><<<grid, 256, 0, stream>>>(Ab, Wt1, b1, G, NN);
        hipMemsetAsync(stats, 0, 512 * sizeof(float), stream);
        k_colstats<<<(NN + 127) / 128, 256, 0, stream>>>(G, stats, NN);
        int t4h = NN * (HID / 4);
        k_bn_relu_ps<<<(t4h + 255) / 256, 256, 0, stream>>>(G, stats, g1, be1, dn_out, Xb, t4h);
    }

    // ---- layer 2 ----
    {
        k_spmm_bf16<HID><<<(NN + 3) / 4, 256, 0, stream>>>(row_ptr, csr_src, Xb, dn_in, Ab, NN);
        dim3 grid((NN + 127) / 128, HID / 64);
        k_gemm_mfma<HID><<<grid, 256, 0, stream>>>(Ab, Wt2, b2, G, NN);
        hipMemsetAsync(stats, 0, 512 * sizeof(float), stream);
        k_colstats<<<(NN + 127) / 128, 256, 0, stream>>>(G, stats, NN);
        int t4h = NN * (HID / 4);
        k_bn_relu<<<(t4h + 255) / 256, 256, 0, stream>>>(G, stats, g2, be2, t4h);
    }

    // ---- Q head ----
    k_qhead<<<(NN + 15) / 16, 256, 0, stream>>>(G, Wa, ba, Wv, bv, out, NN);
}

// Round 4
// 1457.943 us; speedup vs baseline: 11.6025x; 1.1496x over previous
//
#include <hip/hip_runtime.h>
#include <hip/hip_bf16.h>

#define NN 100000
#define NE 3200000
#define HID 256
#define SDIM 128
#define ADIM 64
#define BN_EPS 1e-5f
#define NREP 8

typedef __attribute__((ext_vector_type(8))) short short8;
typedef __attribute__((ext_vector_type(4))) float f32x4;

__device__ __forceinline__ void atomAdd(float* p, float v) { unsafeAtomicAdd(p, v); }
__device__ __forceinline__ float bf2f(ushort u) {
    union { unsigned i; float f; } c; c.i = ((unsigned)u) << 16; return c.f;
}
__device__ __forceinline__ ushort f2bf(float x) {
    __hip_bfloat16 h = __float2bfloat16(x);
    return *reinterpret_cast<ushort*>(&h);
}

// ---------------- degrees into 8 replicas (replica-major to spread line contention) ----------------
__global__ __launch_bounds__(256)
void k_deg(const int* __restrict__ src, const int* __restrict__ dst,
           unsigned* __restrict__ cnt_out, unsigned* __restrict__ cnt_in, int E) {
    int g = blockIdx.x * 256 + threadIdx.x;
    if (g >= E) return;
    int rep = blockIdx.x & (NREP - 1);
    atomicAdd(&cnt_out[(size_t)rep * NN + src[g]], 1u);
    atomicAdd(&cnt_in[(size_t)rep * NN + dst[g]], 1u);
}

// ---------------- sum replicas -> dnorms + total in-degree ----------------
__global__ __launch_bounds__(256)
void k_dnorm_tot(const unsigned* __restrict__ cnt_out, const unsigned* __restrict__ cnt_in,
                 float* __restrict__ dno, float* __restrict__ dni,
                 int* __restrict__ deg_in_tot, int N) {
    int n = blockIdx.x * 256 + threadIdx.x;
    if (n >= N) return;
    unsigned so = 0, si = 0;
    #pragma unroll
    for (int r = 0; r < NREP; ++r) {
        so += cnt_out[(size_t)r * NN + n];
        si += cnt_in[(size_t)r * NN + n];
    }
    dno[n] = rsqrtf(fmaxf((float)so, 1.0f));
    dni[n] = rsqrtf(fmaxf((float)si, 1.0f));
    deg_in_tot[n] = (int)si;
}

// ---------------- single-block exclusive scan over per-node totals -> row_ptr ----------------
__global__ __launch_bounds__(1024)
void k_scan(const int* __restrict__ deg, int* __restrict__ row_ptr, int N) {
    __shared__ int partial[1024];
    const int t = threadIdx.x;
    const int chunk = (N + 1023) / 1024;
    const int lo = t * chunk;
    const int hi = min(lo + chunk, N);
    int s = 0;
    for (int i = lo; i < hi; ++i) s += deg[i];
    partial[t] = s;
    __syncthreads();
    for (int off = 1; off < 1024; off <<= 1) {
        int add = (t >= off) ? partial[t - off] : 0;
        __syncthreads();
        partial[t] += add;
        __syncthreads();
    }
    int run = partial[t] - s;
    for (int i = lo; i < hi; ++i) {
        row_ptr[i] = run;
        run += deg[i];
    }
    if (t == 1023) row_ptr[N] = partial[1023];
}

// ---------------- per-(node,replica) cursors; node bucket stays contiguous ----------------
__global__ __launch_bounds__(256)
void k_cursor(const int* __restrict__ row_ptr, const unsigned* __restrict__ cnt_in,
              unsigned* __restrict__ cursor, int N) {
    int n = blockIdx.x * 256 + threadIdx.x;
    if (n >= N) return;
    unsigned base = (unsigned)row_ptr[n];
    #pragma unroll
    for (int r = 0; r < NREP; ++r) {
        cursor[(size_t)r * NN + n] = base;
        base += cnt_in[(size_t)r * NN + n];
    }
}

// ---------------- scatter edges into CSR via replicated cursors ----------------
__global__ __launch_bounds__(256)
void k_scatter(const int* __restrict__ src, const int* __restrict__ dst,
               unsigned* __restrict__ cursor, int* __restrict__ csr_src, int E) {
    int g = blockIdx.x * 256 + threadIdx.x;
    if (g >= E) return;
    int rep = blockIdx.x & (NREP - 1);
    int d = dst[g];
    unsigned pos = atomicAdd(&cursor[(size_t)rep * NN + d], 1u);
    csr_src[pos] = src[g];
}

// ---------------- W[K,N] fp32 -> Wt[N,K] bf16 ----------------
__global__ __launch_bounds__(256)
void k_wt(const float* __restrict__ W, ushort* __restrict__ Wt, int K, int N) {
    int idx = blockIdx.x * 256 + threadIdx.x;
    if (idx >= K * N) return;
    int n = idx / K, k = idx - n * K;
    Wt[idx] = f2bf(W[(size_t)k * N + n]);
}

// ---------------- feat fp32 -> bf16 prescaled by dno[row] (F=128) ----------------
__global__ __launch_bounds__(256)
void k_prescale_cvt(const float* __restrict__ X, const float* __restrict__ dno,
                    ushort* __restrict__ Y, int total4) {
    int idx = blockIdx.x * 256 + threadIdx.x;
    if (idx >= total4) return;
    int row = idx >> 5;
    float s = dno[row];
    float4 v = reinterpret_cast<const float4*>(X)[idx];
    ushort4 o;
    o.x = f2bf(v.x * s); o.y = f2bf(v.y * s);
    o.z = f2bf(v.z * s); o.w = f2bf(v.w * s);
    reinterpret_cast<ushort4*>(Y)[idx] = o;
}

// ---------------- pull SpMM over bf16 rows ----------------
template <int F>
__global__ __launch_bounds__(256)
void k_spmm_bf16(const int* __restrict__ row_ptr, const int* __restrict__ csr_src,
                 const ushort* __restrict__ X, const float* __restrict__ dni,
                 ushort* __restrict__ Y, int N) {
    const int node = blockIdx.x * 4 + (threadIdx.x >> 6);
    if (node >= N) return;
    const int lane = threadIdx.x & 63;
    const int beg = row_ptr[node];
    const int end = row_ptr[node + 1];
    float acc[4] = {0.f, 0.f, 0.f, 0.f};

    if (F == 256) {
        const ushort* Xl = X + lane * 4;
        int e = beg;
        for (; e + 1 < end; e += 2) {
            int s0 = csr_src[e];
            int s1 = csr_src[e + 1];
            ushort4 v0 = *reinterpret_cast<const ushort4*>(Xl + (size_t)s0 * 256);
            ushort4 v1 = *reinterpret_cast<const ushort4*>(Xl + (size_t)s1 * 256);
            acc[0] += bf2f(v0.x) + bf2f(v1.x);
            acc[1] += bf2f(v0.y) + bf2f(v1.y);
            acc[2] += bf2f(v0.z) + bf2f(v1.z);
            acc[3] += bf2f(v0.w) + bf2f(v1.w);
        }
        if (e < end) {
            int s0 = csr_src[e];
            ushort4 v0 = *reinterpret_cast<const ushort4*>(Xl + (size_t)s0 * 256);
            acc[0] += bf2f(v0.x); acc[1] += bf2f(v0.y);
            acc[2] += bf2f(v0.z); acc[3] += bf2f(v0.w);
        }
        float wi = dni[node];
        ushort4 o;
        o.x = f2bf(acc[0] * wi); o.y = f2bf(acc[1] * wi);
        o.z = f2bf(acc[2] * wi); o.w = f2bf(acc[3] * wi);
        *reinterpret_cast<ushort4*>(Y + (size_t)node * 256 + lane * 4) = o;
    } else {
        const int half = lane >> 5;
        const int l = lane & 31;
        const ushort* Xl = X + l * 4;
        for (int e = beg + half; e < end; e += 2) {
            int s = csr_src[e];
            ushort4 v = *reinterpret_cast<const ushort4*>(Xl + (size_t)s * 128);
            acc[0] += bf2f(v.x); acc[1] += bf2f(v.y);
            acc[2] += bf2f(v.z); acc[3] += bf2f(v.w);
        }
        acc[0] += __shfl_xor(acc[0], 32);
        acc[1] += __shfl_xor(acc[1], 32);
        acc[2] += __shfl_xor(acc[2], 32);
        acc[3] += __shfl_xor(acc[3], 32);
        if (half == 0) {
            float wi = dni[node];
            ushort4 o;
            o.x = f2bf(acc[0] * wi); o.y = f2bf(acc[1] * wi);
            o.z = f2bf(acc[2] * wi); o.w = f2bf(acc[3] * wi);
            *reinterpret_cast<ushort4*>(Y + (size_t)node * 128 + l * 4) = o;
        }
    }
}

// ---------------- MFMA GEMM + fused BN column stats ----------------
// out bf16 [M,256] = A[M,K]bf16 @ Wt[256,K]^T + bias; stats[c], stats[256+c] += col sums.
template <int K>
__global__ __launch_bounds__(256)
void k_gemm_mfma(const ushort* __restrict__ A, const ushort* __restrict__ Wt,
                 const float* __restrict__ bias, ushort* __restrict__ outb,
                 float* __restrict__ stats, int M) {
    __shared__ ushort As[128][40];
    __shared__ ushort Bs[64][40];
    __shared__ float sred[4][2][64];
    const int tid = threadIdx.x;
    const int w = tid >> 6;
    const int lane = tid & 63;
    const int row0 = blockIdx.x * 128;
    const int col0 = blockIdx.y * 64;
    f32x4 acc[2][4] = {};

    const int arow = lane & 15;
    const int ak = (lane >> 4) * 8;

    for (int k0 = 0; k0 < K; k0 += 32) {
        #pragma unroll
        for (int h = 0; h < 2; ++h) {
            int r = (tid >> 2) + 64 * h;
            int kk = (tid & 3) * 8;
            int row = row0 + r;
            int4 v = make_int4(0, 0, 0, 0);
            if (row < M) v = *reinterpret_cast<const int4*>(A + (size_t)row * K + k0 + kk);
            *reinterpret_cast<int4*>(&As[r][kk]) = v;
        }
        {
            int n = tid >> 2;
            int kk = (tid & 3) * 8;
            int4 v = *reinterpret_cast<const int4*>(Wt + (size_t)(col0 + n) * K + k0 + kk);
            *reinterpret_cast<int4*>(&Bs[n][kk]) = v;
        }
        __syncthreads();

        short8 afr[2], bfr[4];
        #pragma unroll
        for (int mi = 0; mi < 2; ++mi)
            afr[mi] = *reinterpret_cast<const short8*>(&As[w * 32 + mi * 16 + arow][ak]);
        #pragma unroll
        for (int ni = 0; ni < 4; ++ni)
            bfr[ni] = *reinterpret_cast<const short8*>(&Bs[ni * 16 + arow][ak]);
        #pragma unroll
        for (int mi = 0; mi < 2; ++mi)
            #pragma unroll
            for (int ni = 0; ni < 4; ++ni)
                acc[mi][ni] = __builtin_amdgcn_mfma_f32_16x16x32_bf16(afr[mi], bfr[ni], acc[mi][ni], 0, 0, 0);
        __syncthreads();
    }

    // epilogue: D col=lane&15, row=(lane>>4)*4+reg; add bias, write bf16, accumulate stats
    const int ncol = lane & 15;
    const int rbase = (lane >> 4) * 4;
    float s1l[4], s2l[4];
    #pragma unroll
    for (int ni = 0; ni < 4; ++ni) { s1l[ni] = 0.f; s2l[ni] = 0.f; }
    #pragma unroll
    for (int ni = 0; ni < 4; ++ni) {
        int col = col0 + ni * 16 + ncol;
        float b = bias[col];
        #pragma unroll
        for (int mi = 0; mi < 2; ++mi) {
            #pragma unroll
            for (int q = 0; q < 4; ++q) {
                int row = row0 + w * 32 + mi * 16 + rbase + q;
                if (row < M) {
                    float val = acc[mi][ni][q] + b;
                    outb[(size_t)row * HID + col] = f2bf(val);
                    s1l[ni] += val;
                    s2l[ni] += val * val;
                }
            }
        }
    }
    #pragma unroll
    for (int ni = 0; ni < 4; ++ni) {
        s1l[ni] += __shfl_xor(s1l[ni], 16);
        s1l[ni] += __shfl_xor(s1l[ni], 32);
        s2l[ni] += __shfl_xor(s2l[ni], 16);
        s2l[ni] += __shfl_xor(s2l[ni], 32);
        if ((lane >> 4) == 0) {
            sred[w][0][ni * 16 + ncol] = s1l[ni];
            sred[w][1][ni * 16 + ncol] = s2l[ni];
        }
    }
    __syncthreads();
    if (tid < 128) {
        int c = tid & 63, st = tid >> 6;
        float v = sred[0][st][c] + sred[1][st][c] + sred[2][st][c] + sred[3][st][c];
        atomAdd(&stats[st * HID + col0 + c], v);
    }
}

// ---------------- BN + ReLU + dno-prescale: Gb bf16 -> Xb bf16 ----------------
__global__ __launch_bounds__(256)
void k_bn_relu_ps(const ushort* __restrict__ Gb, const float* __restrict__ stats,
                  const float* __restrict__ gamma, const float* __restrict__ beta,
                  const float* __restrict__ dno, ushort* __restrict__ Y, int total8) {
    int idx = blockIdx.x * 256 + threadIdx.x;
    if (idx >= total8) return;
    int row = idx >> 5;
    int c0 = (idx & 31) * 8;
    short8 v = *reinterpret_cast<const short8*>(Gb + (size_t)idx * 8);
    float s = dno[row];
    float inv_n = 1.0f / (float)NN;
    short8 o;
    #pragma unroll
    for (int j = 0; j < 8; ++j) {
        int c = c0 + j;
        float mean = stats[c] * inv_n;
        float var = stats[HID + c] * inv_n - mean * mean;
        float sc = gamma[c] * rsqrtf(var + BN_EPS);
        float sh = beta[c] - mean * sc;
        float x = bf2f((ushort)v[j]);
        float y = fmaf(x, sc, sh);
        y = y > 0.f ? y : 0.f;
        o[j] = (short)f2bf(y * s);
    }
    *reinterpret_cast<short8*>(Y + (size_t)idx * 8) = o;
}

// ---------------- fused BN2 + ReLU + dueling Q head ----------------
__global__ __launch_bounds__(256)
void k_bn_qhead(const ushort* __restrict__ Gb, const float* __restrict__ stats,
                const float* __restrict__ gamma, const float* __restrict__ beta,
                const float* __restrict__ Wa, const float* __restrict__ ba,
                const float* __restrict__ Wv, const float* __restrict__ bv,
                float* __restrict__ out, int M) {
    __shared__ float sc_s[HID], sh_s[HID];
    __shared__ float hs[16][HID];
    __shared__ float advs[16][64];
    __shared__ float vparts[16][16];
    __shared__ float means[16], vals[16];
    int tid = threadIdx.x;
    int base = blockIdx.x * 16;
    {
        float inv_n = 1.0f / (float)NN;
        float mean = stats[tid] * inv_n;
        float var = stats[HID + tid] * inv_n - mean * mean;
        float sc = gamma[tid] * rsqrtf(var + BN_EPS);
        sc_s[tid] = sc;
        sh_s[tid] = beta[tid] - mean * sc;
    }
    __syncthreads();
    #pragma unroll
    for (int it = 0; it < 2; ++it) {
        int slot = tid + it * 256;
        int r = slot >> 5, c8 = slot & 31;
        int row = base + r;
        short8 v = {};
        if (row < M) v = *reinterpret_cast<const short8*>(Gb + (size_t)row * HID + c8 * 8);
        #pragma unroll
        for (int j = 0; j < 8; ++j) {
            int c = c8 * 8 + j;
            float x = (row < M) ? bf2f((ushort)v[j]) : 0.f;
            float y = fmaf(x, sc_s[c], sh_s[c]);
            hs[r][c] = y > 0.f ? y : 0.f;
        }
    }
    __syncthreads();
    int col = tid & 63, rg = tid >> 6;
    float b = ba[col];
    float acc[4] = {b, b, b, b};
    for (int k = 0; k < HID; ++k) {
        float w = Wa[k * ADIM + col];
        #pragma unroll
        for (int i = 0; i < 4; ++i) acc[i] = fmaf(hs[rg * 4 + i][k], w, acc[i]);
    }
    #pragma unroll
    for (int i = 0; i < 4; ++i) advs[rg * 4 + i][col] = acc[i];
    int r = tid >> 4, p = tid & 15;
    float vp = 0.f;
    #pragma unroll
    for (int k = 0; k < 16; ++k) vp += hs[r][p * 16 + k] * Wv[p * 16 + k];
    vparts[r][p] = vp;
    __syncthreads();
    if (tid < 16) {
        float s = 0.f;
        #pragma unroll
        for (int c = 0; c < ADIM; ++c) s += advs[tid][c];
        means[tid] = s * (1.0f / ADIM);
        float v = bv[0];
        #pragma unroll
        for (int q = 0; q < 16; ++q) v += vparts[tid][q];
        vals[tid] = v;
    }
    __syncthreads();
    #pragma unroll
    for (int i = 0; i < 4; ++i) {
        int rr = rg * 4 + i;
        int row = base + rr;
        if (row < M) out[(size_t)row * ADIM + col] = vals[rr] + advs[rr][col] - means[rr];
    }
}

extern "C" void kernel_launch(void* const* d_in, const int* in_sizes, int n_in,
                              void* d_out, int out_size, void* d_ws, size_t ws_size,
                              hipStream_t stream) {
    const float* feat = (const float*)d_in[0];
    const int* src = (const int*)d_in[1];
    const int* dst = (const int*)d_in[2];
    const float* W1 = (const float*)d_in[3];
    const float* b1 = (const float*)d_in[4];
    const float* g1 = (const float*)d_in[5];
    const float* be1 = (const float*)d_in[6];
    const float* W2 = (const float*)d_in[7];
    const float* b2 = (const float*)d_in[8];
    const float* g2 = (const float*)d_in[9];
    const float* be2 = (const float*)d_in[10];
    const float* Wa = (const float*)d_in[11];
    const float* ba = (const float*)d_in[12];
    const float* Wv = (const float*)d_in[13];
    const float* bv = (const float*)d_in[14];
    float* out = (float*)d_out;

    char* w = (char*)d_ws;
    unsigned* cnt_out = (unsigned*)w;                       w += (size_t)NREP * NN * 4;
    unsigned* cnt_in  = (unsigned*)w;                       w += (size_t)NREP * NN * 4;
    float* stats      = (float*)w;                          w += 1024 * 4;  // [0:512)=L1, [512:1024)=L2
    float* dn_out     = (float*)w;                          w += NN * 4;
    float* dn_in      = (float*)w;                          w += NN * 4;
    int* deg_in_tot   = (int*)w;                            w += NN * 4;
    int* row_ptr      = (int*)w;                            w += (NN + 4) * 4;
    unsigned* cursor  = (unsigned*)w;                       w += (size_t)NREP * NN * 4;
    int* csr_src      = (int*)w;                            w += (size_t)NE * 4;
    ushort* Wt1       = (ushort*)w;                         w += (size_t)HID * SDIM * 2;
    ushort* Wt2       = (ushort*)w;                         w += (size_t)HID * HID * 2;
    ushort* Xb        = (ushort*)w;                         w += (size_t)NN * HID * 2;
    ushort* Ab        = (ushort*)w;                         w += (size_t)NN * HID * 2;
    ushort* Gb        = (ushort*)w;                         w += (size_t)NN * HID * 2;

    // zero counters + stats (contiguous block)
    hipMemsetAsync(cnt_out, 0, (size_t)2 * NREP * NN * 4 + 1024 * 4, stream);

    // CSR build
    k_deg<<<(NE + 255) / 256, 256, 0, stream>>>(src, dst, cnt_out, cnt_in, NE);
    k_dnorm_tot<<<(NN + 255) / 256, 256, 0, stream>>>(cnt_out, cnt_in, dn_out, dn_in, deg_in_tot, NN);
    k_scan<<<1, 1024, 0, stream>>>(deg_in_tot, row_ptr, NN);
    k_cursor<<<(NN + 255) / 256, 256, 0, stream>>>(row_ptr, cnt_in, cursor, NN);
    k_scatter<<<(NE + 255) / 256, 256, 0, stream>>>(src, dst, cursor, csr_src, NE);

    // weights
    k_wt<<<(SDIM * HID + 255) / 256, 256, 0, stream>>>(W1, Wt1, SDIM, HID);
    k_wt<<<(HID * HID + 255) / 256, 256, 0, stream>>>(W2, Wt2, HID, HID);

    // layer 1
    {
        int t4 = NN * (SDIM / 4);
        k_prescale_cvt<<<(t4 + 255) / 256, 256, 0, stream>>>(feat, dn_out, Xb, t4);
        k_spmm_bf16<SDIM><<<(NN + 3) / 4, 256, 0, stream>>>(row_ptr, csr_src, Xb, dn_in, Ab, NN);
        dim3 grid((NN + 127) / 128, HID / 64);
        k_gemm_mfma<SDIM><<<grid, 256, 0, stream>>>(Ab, Wt1, b1, Gb, stats, NN);
        int t8 = NN * (HID / 8);
        k_bn_relu_ps<<<(t8 + 255) / 256, 256, 0, stream>>>(Gb, stats, g1, be1, dn_out, Xb, t8);
    }

    // layer 2
    {
        k_spmm_bf16<HID><<<(NN + 3) / 4, 256, 0, stream>>>(row_ptr, csr_src, Xb, dn_in, Ab, NN);
        dim3 grid((NN + 127) / 128, HID / 64);
        k_gemm_mfma<HID><<<grid, 256, 0, stream>>>(Ab, Wt2, b2, Gb, stats + 512, NN);
        k_bn_qhead<<<(NN + 15) / 16, 256, 0, stream>>>(Gb, stats + 512, g2, be2, Wa, ba, Wv, bv, out, NN);
    }
}

// Round 5
// 831.041 us; speedup vs baseline: 20.3549x; 1.7544x over previous
//
#include <hip/hip_runtime.h>
#include <hip/hip_bf16.h>

#define NN 100000
#define NE 3200000
#define HID 256
#define SDIM 128
#define ADIM 64
#define BN_EPS 1e-5f

#define BSH 9                       // 512 nodes per bucket
#define NB 196                      // ceil(NN/512)
#define EPB 16384                   // edges per partition block
#define NAB 196                     // ceil(NE/EPB)
#define CAP 24576                   // max edges per bucket staged in LDS (mean 16326, 64 sigma)

typedef __attribute__((ext_vector_type(8))) short short8;
typedef __attribute__((ext_vector_type(4))) float f32x4;

__device__ __forceinline__ void atomAdd(float* p, float v) { unsafeAtomicAdd(p, v); }
__device__ __forceinline__ float bf2f(ushort u) {
    union { unsigned i; float f; } c; c.i = ((unsigned)u) << 16; return c.f;
}
__device__ __forceinline__ ushort f2bf(float x) {
    __hip_bfloat16 h = __float2bfloat16(x);
    return *reinterpret_cast<ushort*>(&h);
}

// ---------------- A0: global bucket histograms (dst + src), line-padded counters ----------------
__global__ __launch_bounds__(1024)
void k_hist(const int* __restrict__ src, const int* __restrict__ dst,
            unsigned* __restrict__ gh_d, unsigned* __restrict__ gh_s, int E) {
    __shared__ unsigned hd[NB], hs[NB];
    int tid = threadIdx.x;
    if (tid < NB) { hd[tid] = 0; hs[tid] = 0; }
    __syncthreads();
    int base = blockIdx.x * EPB;
    int cnt = min(EPB, E - base);
    for (int i = tid; i < cnt; i += 1024) {
        atomicAdd(&hd[dst[base + i] >> BSH], 1u);
        atomicAdd(&hs[src[base + i] >> BSH], 1u);
    }
    __syncthreads();
    if (tid < NB) {
        if (hd[tid]) atomicAdd(&gh_d[tid * 16], hd[tid]);
        if (hs[tid]) atomicAdd(&gh_s[tid * 16], hs[tid]);
    }
}

// ---------------- scan bucket totals -> bases + cursors; row_ptr[NN]=E ----------------
__global__ __launch_bounds__(256)
void k_scan_b(const unsigned* __restrict__ gh_d, const unsigned* __restrict__ gh_s,
              unsigned* __restrict__ gcur_d, unsigned* __restrict__ gcur_s,
              unsigned* __restrict__ bbase_d, unsigned* __restrict__ bbase_s,
              int* __restrict__ row_ptr) {
    __shared__ unsigned v[256];
    int t = threadIdx.x;
    unsigned x = (t < NB) ? gh_d[t * 16] : 0;
    v[t] = x; __syncthreads();
    for (int off = 1; off < 256; off <<= 1) {
        unsigned a = (t >= off) ? v[t - off] : 0;
        __syncthreads(); v[t] += a; __syncthreads();
    }
    if (t < NB) { bbase_d[t] = v[t] - x; gcur_d[t * 16] = v[t] - x; }
    if (t == 255) { bbase_d[NB] = v[255]; row_ptr[NN] = (int)v[255]; }
    __syncthreads();
    unsigned y = (t < NB) ? gh_s[t * 16] : 0;
    v[t] = y; __syncthreads();
    for (int off = 1; off < 256; off <<= 1) {
        unsigned a = (t >= off) ? v[t - off] : 0;
        __syncthreads(); v[t] += a; __syncthreads();
    }
    if (t < NB) { bbase_s[t] = v[t] - y; gcur_s[t * 16] = v[t] - y; }
    if (t == 255) bbase_s[NB] = v[255];
}

// ---------------- A1: partition edges into buckets with LDS compaction (coalesced appends) ----------------
__global__ __launch_bounds__(1024)
void k_part(const int* __restrict__ src, const int* __restrict__ dst,
            unsigned* __restrict__ gcur_d, unsigned* __restrict__ gcur_s,
            unsigned* __restrict__ outd, ushort* __restrict__ outs, int E) {
    __shared__ unsigned hd[NB], hs[NB], ld_[NB], ls_[NB], cd[NB], cs[NB], bd[NB], bs[NB];
    __shared__ unsigned sv[256];
    __shared__ unsigned stage_d[EPB];
    __shared__ ushort stage_s[EPB];
    __shared__ unsigned char sbd[EPB], sbs[EPB];
    const int tid = threadIdx.x;
    const int base = blockIdx.x * EPB;
    const int cnt = min(EPB, E - base);
    if (tid < NB) { hd[tid] = 0; hs[tid] = 0; }
    __syncthreads();

    int es[16], ed[16];
    #pragma unroll
    for (int i = 0; i < 16; ++i) {
        int g = tid + i * 1024;
        if (g < cnt) { es[i] = src[base + g]; ed[i] = dst[base + g]; }
        else { es[i] = -1; ed[i] = -1; }
    }
    #pragma unroll
    for (int i = 0; i < 16; ++i)
        if (ed[i] >= 0) {
            atomicAdd(&hd[ed[i] >> BSH], 1u);
            atomicAdd(&hs[es[i] >> BSH], 1u);
        }
    __syncthreads();

    // exclusive scans of hd, hs; reserve global chunks
    {
        unsigned x = (tid < NB) ? hd[tid] : 0;
        if (tid < 256) sv[tid] = x;
        __syncthreads();
        for (int off = 1; off < 256; off <<= 1) {
            unsigned a = 0;
            if (tid < 256 && tid >= off) a = sv[tid - off];
            __syncthreads();
            if (tid < 256) sv[tid] += a;
            __syncthreads();
        }
        if (tid < NB) {
            ld_[tid] = sv[tid] - x; cd[tid] = sv[tid] - x;
            bd[tid] = atomicAdd(&gcur_d[tid * 16], hd[tid]);
        }
        __syncthreads();
        unsigned y = (tid < NB) ? hs[tid] : 0;
        if (tid < 256) sv[tid] = y;
        __syncthreads();
        for (int off = 1; off < 256; off <<= 1) {
            unsigned a = 0;
            if (tid < 256 && tid >= off) a = sv[tid - off];
            __syncthreads();
            if (tid < 256) sv[tid] += a;
            __syncthreads();
        }
        if (tid < NB) {
            ls_[tid] = sv[tid] - y; cs[tid] = sv[tid] - y;
            bs[tid] = atomicAdd(&gcur_s[tid * 16], hs[tid]);
        }
        __syncthreads();
    }

    // LDS scatter into bucket-grouped staging
    #pragma unroll
    for (int i = 0; i < 16; ++i)
        if (ed[i] >= 0) {
            int b = ed[i] >> BSH;
            unsigned p = atomicAdd(&cd[b], 1u);
            stage_d[p] = ((unsigned)(ed[i] & ((1 << BSH) - 1)) << 17) | (unsigned)es[i];
            sbd[p] = (unsigned char)b;
            int b2 = es[i] >> BSH;
            unsigned p2 = atomicAdd(&cs[b2], 1u);
            stage_s[p2] = (ushort)(es[i] & ((1 << BSH) - 1));
            sbs[p2] = (unsigned char)b2;
        }
    __syncthreads();

    // stream chunks to global (mostly-coalesced)
    for (int i = tid; i < cnt; i += 1024) {
        unsigned b = sbd[i];
        outd[bd[b] + (unsigned)i - ld_[b]] = stage_d[i];
        unsigned b2 = sbs[i];
        outs[bs[b2] + (unsigned)i - ls_[b2]] = stage_s[i];
    }
}

// ---------------- B: per-bucket CSR finalize (row_ptr, dni, node-sorted csr_src) ----------------
__global__ __launch_bounds__(1024)
void k_csr(const unsigned* __restrict__ outd, const unsigned* __restrict__ bbase_d,
           int* __restrict__ row_ptr, int* __restrict__ csr_src, float* __restrict__ dni) {
    __shared__ unsigned h[512], sc[512];
    __shared__ int sorted[CAP];
    const int tid = threadIdx.x, b = blockIdx.x;
    const unsigned beg = bbase_d[b], end = bbase_d[b + 1];
    const int cnt = (int)(end - beg);
    if (tid < 512) h[tid] = 0;
    __syncthreads();
    for (int i = tid; i < cnt; i += 1024) atomicAdd(&h[outd[beg + i] >> 17], 1u);
    __syncthreads();
    unsigned my = 0;
    if (tid < 512) { my = h[tid]; sc[tid] = my; }
    __syncthreads();
    for (int off = 1; off < 512; off <<= 1) {
        unsigned a = 0;
        if (tid < 512 && tid >= off) a = sc[tid - off];
        __syncthreads();
        if (tid < 512) sc[tid] += a;
        __syncthreads();
    }
    const int n0 = b << BSH;
    const int nb = min(512, NN - n0);
    unsigned excl = 0;
    if (tid < 512) excl = sc[tid] - my;
    __syncthreads();
    if (tid < 512) h[tid] = excl;  // becomes cursor
    if (tid < nb) {
        row_ptr[n0 + tid] = (int)(beg + excl);
        dni[n0 + tid] = rsqrtf(fmaxf((float)my, 1.0f));
    }
    __syncthreads();
    for (int i = tid; i < cnt; i += 1024) {
        unsigned p = outd[beg + i];
        unsigned pos = atomicAdd(&h[p >> 17], 1u);
        sorted[pos] = (int)(p & 0x1FFFFu);
    }
    __syncthreads();
    for (int i = tid; i < cnt; i += 1024) csr_src[beg + i] = sorted[i];
}

// ---------------- out-degrees -> dno (per src bucket) ----------------
__global__ __launch_bounds__(1024)
void k_degout(const ushort* __restrict__ outs, const unsigned* __restrict__ bbase_s,
              float* __restrict__ dno) {
    __shared__ unsigned h[512];
    const int tid = threadIdx.x, b = blockIdx.x;
    const unsigned beg = bbase_s[b], end = bbase_s[b + 1];
    const int cnt = (int)(end - beg);
    if (tid < 512) h[tid] = 0;
    __syncthreads();
    for (int i = tid; i < cnt; i += 1024) atomicAdd(&h[outs[beg + i]], 1u);
    __syncthreads();
    const int n0 = b << BSH;
    const int nb = min(512, NN - n0);
    if (tid < nb) dno[n0 + tid] = rsqrtf(fmaxf((float)h[tid], 1.0f));
}

// ---------------- W[K,N] fp32 -> Wt[N,K] bf16 ----------------
__global__ __launch_bounds__(256)
void k_wt(const float* __restrict__ W, ushort* __restrict__ Wt, int K, int N) {
    int idx = blockIdx.x * 256 + threadIdx.x;
    if (idx >= K * N) return;
    int n = idx / K, k = idx - n * K;
    Wt[idx] = f2bf(W[(size_t)k * N + n]);
}

// ---------------- feat fp32 -> bf16 prescaled by dno[row] (F=128) ----------------
__global__ __launch_bounds__(256)
void k_prescale_cvt(const float* __restrict__ X, const float* __restrict__ dno,
                    ushort* __restrict__ Y, int total4) {
    int idx = blockIdx.x * 256 + threadIdx.x;
    if (idx >= total4) return;
    int row = idx >> 5;
    float s = dno[row];
    float4 v = reinterpret_cast<const float4*>(X)[idx];
    ushort4 o;
    o.x = f2bf(v.x * s); o.y = f2bf(v.y * s);
    o.z = f2bf(v.z * s); o.w = f2bf(v.w * s);
    reinterpret_cast<ushort4*>(Y)[idx] = o;
}

// ---------------- pull SpMM over bf16 rows ----------------
template <int F>
__global__ __launch_bounds__(256)
void k_spmm_bf16(const int* __restrict__ row_ptr, const int* __restrict__ csr_src,
                 const ushort* __restrict__ X, const float* __restrict__ dni,
                 ushort* __restrict__ Y, int N) {
    const int node = blockIdx.x * 4 + (threadIdx.x >> 6);
    if (node >= N) return;
    const int lane = threadIdx.x & 63;
    const int beg = row_ptr[node];
    const int end = row_ptr[node + 1];
    float acc[4] = {0.f, 0.f, 0.f, 0.f};

    if (F == 256) {
        const ushort* Xl = X + lane * 4;
        int e = beg;
        for (; e + 1 < end; e += 2) {
            int s0 = csr_src[e];
            int s1 = csr_src[e + 1];
            ushort4 v0 = *reinterpret_cast<const ushort4*>(Xl + (size_t)s0 * 256);
            ushort4 v1 = *reinterpret_cast<const ushort4*>(Xl + (size_t)s1 * 256);
            acc[0] += bf2f(v0.x) + bf2f(v1.x);
            acc[1] += bf2f(v0.y) + bf2f(v1.y);
            acc[2] += bf2f(v0.z) + bf2f(v1.z);
            acc[3] += bf2f(v0.w) + bf2f(v1.w);
        }
        if (e < end) {
            int s0 = csr_src[e];
            ushort4 v0 = *reinterpret_cast<const ushort4*>(Xl + (size_t)s0 * 256);
            acc[0] += bf2f(v0.x); acc[1] += bf2f(v0.y);
            acc[2] += bf2f(v0.z); acc[3] += bf2f(v0.w);
        }
        float wi = dni[node];
        ushort4 o;
        o.x = f2bf(acc[0] * wi); o.y = f2bf(acc[1] * wi);
        o.z = f2bf(acc[2] * wi); o.w = f2bf(acc[3] * wi);
        *reinterpret_cast<ushort4*>(Y + (size_t)node * 256 + lane * 4) = o;
    } else {
        const int half = lane >> 5;
        const int l = lane & 31;
        const ushort* Xl = X + l * 4;
        for (int e = beg + half; e < end; e += 2) {
            int s = csr_src[e];
            ushort4 v = *reinterpret_cast<const ushort4*>(Xl + (size_t)s * 128);
            acc[0] += bf2f(v.x); acc[1] += bf2f(v.y);
            acc[2] += bf2f(v.z); acc[3] += bf2f(v.w);
        }
        acc[0] += __shfl_xor(acc[0], 32);
        acc[1] += __shfl_xor(acc[1], 32);
        acc[2] += __shfl_xor(acc[2], 32);
        acc[3] += __shfl_xor(acc[3], 32);
        if (half == 0) {
            float wi = dni[node];
            ushort4 o;
            o.x = f2bf(acc[0] * wi); o.y = f2bf(acc[1] * wi);
            o.z = f2bf(acc[2] * wi); o.w = f2bf(acc[3] * wi);
            *reinterpret_cast<ushort4*>(Y + (size_t)node * 128 + l * 4) = o;
        }
    }
}

// ---------------- MFMA GEMM + fused BN column stats ----------------
template <int K>
__global__ __launch_bounds__(256)
void k_gemm_mfma(const ushort* __restrict__ A, const ushort* __restrict__ Wt,
                 const float* __restrict__ bias, ushort* __restrict__ outb,
                 float* __restrict__ stats, int M) {
    __shared__ ushort As[128][40];
    __shared__ ushort Bs[64][40];
    __shared__ float sred[4][2][64];
    const int tid = threadIdx.x;
    const int w = tid >> 6;
    const int lane = tid & 63;
    const int row0 = blockIdx.x * 128;
    const int col0 = blockIdx.y * 64;
    f32x4 acc[2][4] = {};

    const int arow = lane & 15;
    const int ak = (lane >> 4) * 8;

    for (int k0 = 0; k0 < K; k0 += 32) {
        #pragma unroll
        for (int h = 0; h < 2; ++h) {
            int r = (tid >> 2) + 64 * h;
            int kk = (tid & 3) * 8;
            int row = row0 + r;
            int4 v = make_int4(0, 0, 0, 0);
            if (row < M) v = *reinterpret_cast<const int4*>(A + (size_t)row * K + k0 + kk);
            *reinterpret_cast<int4*>(&As[r][kk]) = v;
        }
        {
            int n = tid >> 2;
            int kk = (tid & 3) * 8;
            int4 v = *reinterpret_cast<const int4*>(Wt + (size_t)(col0 + n) * K + k0 + kk);
            *reinterpret_cast<int4*>(&Bs[n][kk]) = v;
        }
        __syncthreads();

        short8 afr[2], bfr[4];
        #pragma unroll
        for (int mi = 0; mi < 2; ++mi)
            afr[mi] = *reinterpret_cast<const short8*>(&As[w * 32 + mi * 16 + arow][ak]);
        #pragma unroll
        for (int ni = 0; ni < 4; ++ni)
            bfr[ni] = *reinterpret_cast<const short8*>(&Bs[ni * 16 + arow][ak]);
        #pragma unroll
        for (int mi = 0; mi < 2; ++mi)
            #pragma unroll
            for (int ni = 0; ni < 4; ++ni)
                acc[mi][ni] = __builtin_amdgcn_mfma_f32_16x16x32_bf16(afr[mi], bfr[ni], acc[mi][ni], 0, 0, 0);
        __syncthreads();
    }

    const int ncol = lane & 15;
    const int rbase = (lane >> 4) * 4;
    float s1l[4], s2l[4];
    #pragma unroll
    for (int ni = 0; ni < 4; ++ni) { s1l[ni] = 0.f; s2l[ni] = 0.f; }
    #pragma unroll
    for (int ni = 0; ni < 4; ++ni) {
        int col = col0 + ni * 16 + ncol;
        float b = bias[col];
        #pragma unroll
        for (int mi = 0; mi < 2; ++mi) {
            #pragma unroll
            for (int q = 0; q < 4; ++q) {
                int row = row0 + w * 32 + mi * 16 + rbase + q;
                if (row < M) {
                    float val = acc[mi][ni][q] + b;
                    outb[(size_t)row * HID + col] = f2bf(val);
                    s1l[ni] += val;
                    s2l[ni] += val * val;
                }
            }
        }
    }
    #pragma unroll
    for (int ni = 0; ni < 4; ++ni) {
        s1l[ni] += __shfl_xor(s1l[ni], 16);
        s1l[ni] += __shfl_xor(s1l[ni], 32);
        s2l[ni] += __shfl_xor(s2l[ni], 16);
        s2l[ni] += __shfl_xor(s2l[ni], 32);
        if ((lane >> 4) == 0) {
            sred[w][0][ni * 16 + ncol] = s1l[ni];
            sred[w][1][ni * 16 + ncol] = s2l[ni];
        }
    }
    __syncthreads();
    if (tid < 128) {
        int c = tid & 63, st = tid >> 6;
        float v = sred[0][st][c] + sred[1][st][c] + sred[2][st][c] + sred[3][st][c];
        atomAdd(&stats[st * HID + col0 + c], v);
    }
}

// ---------------- BN + ReLU + dno-prescale: Gb bf16 -> Xb bf16 ----------------
__global__ __launch_bounds__(256)
void k_bn_relu_ps(const ushort* __restrict__ Gb, const float* __restrict__ stats,
                  const float* __restrict__ gamma, const float* __restrict__ beta,
                  const float* __restrict__ dno, ushort* __restrict__ Y, int total8) {
    int idx = blockIdx.x * 256 + threadIdx.x;
    if (idx >= total8) return;
    int row = idx >> 5;
    int c0 = (idx & 31) * 8;
    short8 v = *reinterpret_cast<const short8*>(Gb + (size_t)idx * 8);
    float s = dno[row];
    float inv_n = 1.0f / (float)NN;
    short8 o;
    #pragma unroll
    for (int j = 0; j < 8; ++j) {
        int c = c0 + j;
        float mean = stats[c] * inv_n;
        float var = stats[HID + c] * inv_n - mean * mean;
        float sc = gamma[c] * rsqrtf(var + BN_EPS);
        float sh = beta[c] - mean * sc;
        float x = bf2f((ushort)v[j]);
        float y = fmaf(x, sc, sh);
        y = y > 0.f ? y : 0.f;
        o[j] = (short)f2bf(y * s);
    }
    *reinterpret_cast<short8*>(Y + (size_t)idx * 8) = o;
}

// ---------------- fused BN2 + ReLU + dueling Q head ----------------
__global__ __launch_bounds__(256)
void k_bn_qhead(const ushort* __restrict__ Gb, const float* __restrict__ stats,
                const float* __restrict__ gamma, const float* __restrict__ beta,
                const float* __restrict__ Wa, const float* __restrict__ ba,
                const float* __restrict__ Wv, const float* __restrict__ bv,
                float* __restrict__ out, int M) {
    __shared__ float sc_s[HID], sh_s[HID];
    __shared__ float hs[16][HID];
    __shared__ float advs[16][64];
    __shared__ float vparts[16][16];
    __shared__ float means[16], vals[16];
    int tid = threadIdx.x;
    int base = blockIdx.x * 16;
    {
        float inv_n = 1.0f / (float)NN;
        float mean = stats[tid] * inv_n;
        float var = stats[HID + tid] * inv_n - mean * mean;
        float sc = gamma[tid] * rsqrtf(var + BN_EPS);
        sc_s[tid] = sc;
        sh_s[tid] = beta[tid] - mean * sc;
    }
    __syncthreads();
    #pragma unroll
    for (int it = 0; it < 2; ++it) {
        int slot = tid + it * 256;
        int r = slot >> 5, c8 = slot & 31;
        int row = base + r;
        short8 v = {};
        if (row < M) v = *reinterpret_cast<const short8*>(Gb + (size_t)row * HID + c8 * 8);
        #pragma unroll
        for (int j = 0; j < 8; ++j) {
            int c = c8 * 8 + j;
            float x = (row < M) ? bf2f((ushort)v[j]) : 0.f;
            float y = fmaf(x, sc_s[c], sh_s[c]);
            hs[r][c] = y > 0.f ? y : 0.f;
        }
    }
    __syncthreads();
    int col = tid & 63, rg = tid >> 6;
    float b = ba[col];
    float acc[4] = {b, b, b, b};
    for (int k = 0; k < HID; ++k) {
        float w = Wa[k * ADIM + col];
        #pragma unroll
        for (int i = 0; i < 4; ++i) acc[i] = fmaf(hs[rg * 4 + i][k], w, acc[i]);
    }
    #pragma unroll
    for (int i = 0; i < 4; ++i) advs[rg * 4 + i][col] = acc[i];
    int r = tid >> 4, p = tid & 15;
    float vp = 0.f;
    #pragma unroll
    for (int k = 0; k < 16; ++k) vp += hs[r][p * 16 + k] * Wv[p * 16 + k];
    vparts[r][p] = vp;
    __syncthreads();
    if (tid < 16) {
        float s = 0.f;
        #pragma unroll
        for (int c = 0; c < ADIM; ++c) s += advs[tid][c];
        means[tid] = s * (1.0f / ADIM);
        float v = bv[0];
        #pragma unroll
        for (int q = 0; q < 16; ++q) v += vparts[tid][q];
        vals[tid] = v;
    }
    __syncthreads();
    #pragma unroll
    for (int i = 0; i < 4; ++i) {
        int rr = rg * 4 + i;
        int row = base + rr;
        if (row < M) out[(size_t)row * ADIM + col] = vals[rr] + advs[rr][col] - means[rr];
    }
}

extern "C" void kernel_launch(void* const* d_in, const int* in_sizes, int n_in,
                              void* d_out, int out_size, void* d_ws, size_t ws_size,
                              hipStream_t stream) {
    const float* feat = (const float*)d_in[0];
    const int* src = (const int*)d_in[1];
    const int* dst = (const int*)d_in[2];
    const float* W1 = (const float*)d_in[3];
    const float* b1 = (const float*)d_in[4];
    const float* g1 = (const float*)d_in[5];
    const float* be1 = (const float*)d_in[6];
    const float* W2 = (const float*)d_in[7];
    const float* b2 = (const float*)d_in[8];
    const float* g2 = (const float*)d_in[9];
    const float* be2 = (const float*)d_in[10];
    const float* Wa = (const float*)d_in[11];
    const float* ba = (const float*)d_in[12];
    const float* Wv = (const float*)d_in[13];
    const float* bv = (const float*)d_in[14];
    float* out = (float*)d_out;

    char* w = (char*)d_ws;
    unsigned* gh_d   = (unsigned*)w;  w += (size_t)NB * 16 * 4;
    unsigned* gh_s   = (unsigned*)w;  w += (size_t)NB * 16 * 4;
    float* stats     = (float*)w;     w += 1024 * 4;
    unsigned* gcur_d = (unsigned*)w;  w += (size_t)NB * 16 * 4;
    unsigned* gcur_s = (unsigned*)w;  w += (size_t)NB * 16 * 4;
    unsigned* bbase_d= (unsigned*)w;  w += (NB + 4) * 4;
    unsigned* bbase_s= (unsigned*)w;  w += (NB + 4) * 4;
    float* dn_out    = (float*)w;     w += (size_t)NN * 4;
    float* dn_in     = (float*)w;     w += (size_t)NN * 4;
    int* row_ptr     = (int*)w;       w += (size_t)(NN + 4) * 4;
    unsigned* outd   = (unsigned*)w;  w += (size_t)NE * 4;
    ushort* outs     = (ushort*)w;    w += (size_t)NE * 2;
    int* csr_src     = (int*)w;       w += (size_t)NE * 4;
    ushort* Wt1      = (ushort*)w;    w += (size_t)HID * SDIM * 2;
    ushort* Wt2      = (ushort*)w;    w += (size_t)HID * HID * 2;
    ushort* Xb       = (ushort*)w;    w += (size_t)NN * HID * 2;
    ushort* Ab       = (ushort*)w;    w += (size_t)NN * HID * 2;
    ushort* Gb       = (ushort*)w;    w += (size_t)NN * HID * 2;

    // zero bucket histograms + stats (contiguous)
    hipMemsetAsync(gh_d, 0, (size_t)2 * NB * 16 * 4 + 1024 * 4, stream);

    // CSR build via two-level counting sort
    k_hist<<<NAB, 1024, 0, stream>>>(src, dst, gh_d, gh_s, NE);
    k_scan_b<<<1, 256, 0, stream>>>(gh_d, gh_s, gcur_d, gcur_s, bbase_d, bbase_s, row_ptr);
    k_part<<<NAB, 1024, 0, stream>>>(src, dst, gcur_d, gcur_s, outd, outs, NE);
    k_csr<<<NB, 1024, 0, stream>>>(outd, bbase_d, row_ptr, csr_src, dn_in);
    k_degout<<<NB, 1024, 0, stream>>>(outs, bbase_s, dn_out);

    // weights
    k_wt<<<(SDIM * HID + 255) / 256, 256, 0, stream>>>(W1, Wt1, SDIM, HID);
    k_wt<<<(HID * HID + 255) / 256, 256, 0, stream>>>(W2, Wt2, HID, HID);

    // layer 1
    {
        int t4 = NN * (SDIM / 4);
        k_prescale_cvt<<<(t4 + 255) / 256, 256, 0, stream>>>(feat, dn_out, Xb, t4);
        k_spmm_bf16<SDIM><<<(NN + 3) / 4, 256, 0, stream>>>(row_ptr, csr_src, Xb, dn_in, Ab, NN);
        dim3 grid((NN + 127) / 128, HID / 64);
        k_gemm_mfma<SDIM><<<grid, 256, 0, stream>>>(Ab, Wt1, b1, Gb, stats, NN);
        int t8 = NN * (HID / 8);
        k_bn_relu_ps<<<(t8 + 255) / 256, 256, 0, stream>>>(Gb, stats, g1, be1, dn_out, Xb, t8);
    }

    // layer 2
    {
        k_spmm_bf16<HID><<<(NN + 3) / 4, 256, 0, stream>>>(row_ptr, csr_src, Xb, dn_in, Ab, NN);
        dim3 grid((NN + 127) / 128, HID / 64);
        k_gemm_mfma<HID><<<grid, 256, 0, stream>>>(Ab, Wt2, b2, Gb, stats + 512, NN);
        k_bn_qhead<<<(NN + 15) / 16, 256, 0, stream>>>(Gb, stats + 512, g2, be2, Wa, ba, Wv, bv, out, NN);
    }
}

// Round 6
// 740.212 us; speedup vs baseline: 22.8526x; 1.1227x over previous
//
#include <hip/hip_runtime.h>
#include <hip/hip_bf16.h>

#define NN 100000
#define NE 3200000
#define HID 256
#define SDIM 128
#define ADIM 64
#define BN_EPS 1e-5f

#define BSH 9                       // 512 nodes per bucket
#define NB 196                      // ceil(NN/512)
#define EPB 16384                   // edges per partition block
#define NAB 196                     // ceil(NE/EPB)
#define CAP 24576                   // max edges per bucket staged in LDS

typedef __attribute__((ext_vector_type(8))) short short8;
typedef __attribute__((ext_vector_type(4))) float f32x4;

__device__ __forceinline__ void atomAdd(float* p, float v) { unsafeAtomicAdd(p, v); }
__device__ __forceinline__ float bf2f(ushort u) {
    union { unsigned i; float f; } c; c.i = ((unsigned)u) << 16; return c.f;
}
__device__ __forceinline__ ushort f2bf(float x) {
    __hip_bfloat16 h = __float2bfloat16(x);
    return *reinterpret_cast<ushort*>(&h);
}

// ---------------- A0: global bucket histograms (dst + src) ----------------
__global__ __launch_bounds__(1024)
void k_hist(const int* __restrict__ src, const int* __restrict__ dst,
            unsigned* __restrict__ gh_d, unsigned* __restrict__ gh_s, int E) {
    __shared__ unsigned hd[NB], hs[NB];
    int tid = threadIdx.x;
    if (tid < NB) { hd[tid] = 0; hs[tid] = 0; }
    __syncthreads();
    int base = blockIdx.x * EPB;
    int cnt = min(EPB, E - base);
    for (int i = tid; i < cnt; i += 1024) {
        atomicAdd(&hd[dst[base + i] >> BSH], 1u);
        atomicAdd(&hs[src[base + i] >> BSH], 1u);
    }
    __syncthreads();
    if (tid < NB) {
        if (hd[tid]) atomicAdd(&gh_d[tid * 16], hd[tid]);
        if (hs[tid]) atomicAdd(&gh_s[tid * 16], hs[tid]);
    }
}

// ---------------- scan bucket totals -> bases + cursors ----------------
__global__ __launch_bounds__(256)
void k_scan_b(const unsigned* __restrict__ gh_d, const unsigned* __restrict__ gh_s,
              unsigned* __restrict__ gcur_d, unsigned* __restrict__ gcur_s,
              unsigned* __restrict__ bbase_d, unsigned* __restrict__ bbase_s,
              int* __restrict__ row_ptr) {
    __shared__ unsigned v[256];
    int t = threadIdx.x;
    unsigned x = (t < NB) ? gh_d[t * 16] : 0;
    v[t] = x; __syncthreads();
    for (int off = 1; off < 256; off <<= 1) {
        unsigned a = (t >= off) ? v[t - off] : 0;
        __syncthreads(); v[t] += a; __syncthreads();
    }
    if (t < NB) { bbase_d[t] = v[t] - x; gcur_d[t * 16] = v[t] - x; }
    if (t == 255) { bbase_d[NB] = v[255]; row_ptr[NN] = (int)v[255]; }
    __syncthreads();
    unsigned y = (t < NB) ? gh_s[t * 16] : 0;
    v[t] = y; __syncthreads();
    for (int off = 1; off < 256; off <<= 1) {
        unsigned a = (t >= off) ? v[t - off] : 0;
        __syncthreads(); v[t] += a; __syncthreads();
    }
    if (t < NB) { bbase_s[t] = v[t] - y; gcur_s[t * 16] = v[t] - y; }
    if (t == 255) bbase_s[NB] = v[255];
}

// ---------------- A1: partition edges into buckets ----------------
__global__ __launch_bounds__(1024)
void k_part(const int* __restrict__ src, const int* __restrict__ dst,
            unsigned* __restrict__ gcur_d, unsigned* __restrict__ gcur_s,
            unsigned* __restrict__ outd, ushort* __restrict__ outs, int E) {
    __shared__ unsigned hd[NB], hs[NB], ld_[NB], ls_[NB], cd[NB], cs[NB], bd[NB], bs[NB];
    __shared__ unsigned sv[256];
    __shared__ unsigned stage_d[EPB];
    __shared__ ushort stage_s[EPB];
    __shared__ unsigned char sbd[EPB], sbs[EPB];
    const int tid = threadIdx.x;
    const int base = blockIdx.x * EPB;
    const int cnt = min(EPB, E - base);
    if (tid < NB) { hd[tid] = 0; hs[tid] = 0; }
    __syncthreads();

    int es[16], ed[16];
    #pragma unroll
    for (int i = 0; i < 16; ++i) {
        int g = tid + i * 1024;
        if (g < cnt) { es[i] = src[base + g]; ed[i] = dst[base + g]; }
        else { es[i] = -1; ed[i] = -1; }
    }
    #pragma unroll
    for (int i = 0; i < 16; ++i)
        if (ed[i] >= 0) {
            atomicAdd(&hd[ed[i] >> BSH], 1u);
            atomicAdd(&hs[es[i] >> BSH], 1u);
        }
    __syncthreads();

    {
        unsigned x = (tid < NB) ? hd[tid] : 0;
        if (tid < 256) sv[tid] = x;
        __syncthreads();
        for (int off = 1; off < 256; off <<= 1) {
            unsigned a = 0;
            if (tid < 256 && tid >= off) a = sv[tid - off];
            __syncthreads();
            if (tid < 256) sv[tid] += a;
            __syncthreads();
        }
        if (tid < NB) {
            ld_[tid] = sv[tid] - x; cd[tid] = sv[tid] - x;
            bd[tid] = atomicAdd(&gcur_d[tid * 16], hd[tid]);
        }
        __syncthreads();
        unsigned y = (tid < NB) ? hs[tid] : 0;
        if (tid < 256) sv[tid] = y;
        __syncthreads();
        for (int off = 1; off < 256; off <<= 1) {
            unsigned a = 0;
            if (tid < 256 && tid >= off) a = sv[tid - off];
            __syncthreads();
            if (tid < 256) sv[tid] += a;
            __syncthreads();
        }
        if (tid < NB) {
            ls_[tid] = sv[tid] - y; cs[tid] = sv[tid] - y;
            bs[tid] = atomicAdd(&gcur_s[tid * 16], hs[tid]);
        }
        __syncthreads();
    }

    #pragma unroll
    for (int i = 0; i < 16; ++i)
        if (ed[i] >= 0) {
            int b = ed[i] >> BSH;
            unsigned p = atomicAdd(&cd[b], 1u);
            stage_d[p] = ((unsigned)(ed[i] & ((1 << BSH) - 1)) << 17) | (unsigned)es[i];
            sbd[p] = (unsigned char)b;
            int b2 = es[i] >> BSH;
            unsigned p2 = atomicAdd(&cs[b2], 1u);
            stage_s[p2] = (ushort)(es[i] & ((1 << BSH) - 1));
            sbs[p2] = (unsigned char)b2;
        }
    __syncthreads();

    for (int i = tid; i < cnt; i += 1024) {
        unsigned b = sbd[i];
        outd[bd[b] + (unsigned)i - ld_[b]] = stage_d[i];
        unsigned b2 = sbs[i];
        outs[bs[b2] + (unsigned)i - ls_[b2]] = stage_s[i];
    }
}

// ---------------- B: per-bucket CSR finalize ----------------
__global__ __launch_bounds__(1024)
void k_csr(const unsigned* __restrict__ outd, const unsigned* __restrict__ bbase_d,
           int* __restrict__ row_ptr, int* __restrict__ csr_src, float* __restrict__ dni) {
    __shared__ unsigned h[512], sc[512];
    __shared__ int sorted[CAP];
    const int tid = threadIdx.x, b = blockIdx.x;
    const unsigned beg = bbase_d[b], end = bbase_d[b + 1];
    const int cnt = (int)(end - beg);
    if (tid < 512) h[tid] = 0;
    __syncthreads();
    for (int i = tid; i < cnt; i += 1024) atomicAdd(&h[outd[beg + i] >> 17], 1u);
    __syncthreads();
    unsigned my = 0;
    if (tid < 512) { my = h[tid]; sc[tid] = my; }
    __syncthreads();
    for (int off = 1; off < 512; off <<= 1) {
        unsigned a = 0;
        if (tid < 512 && tid >= off) a = sc[tid - off];
        __syncthreads();
        if (tid < 512) sc[tid] += a;
        __syncthreads();
    }
    const int n0 = b << BSH;
    const int nb = min(512, NN - n0);
    unsigned excl = 0;
    if (tid < 512) excl = sc[tid] - my;
    __syncthreads();
    if (tid < 512) h[tid] = excl;
    if (tid < nb) {
        row_ptr[n0 + tid] = (int)(beg + excl);
        dni[n0 + tid] = rsqrtf(fmaxf((float)my, 1.0f));
    }
    __syncthreads();
    for (int i = tid; i < cnt; i += 1024) {
        unsigned p = outd[beg + i];
        unsigned pos = atomicAdd(&h[p >> 17], 1u);
        sorted[pos] = (int)(p & 0x1FFFFu);
    }
    __syncthreads();
    for (int i = tid; i < cnt; i += 1024) csr_src[beg + i] = sorted[i];
}

// ---------------- out-degrees -> dno ----------------
__global__ __launch_bounds__(1024)
void k_degout(const ushort* __restrict__ outs, const unsigned* __restrict__ bbase_s,
              float* __restrict__ dno) {
    __shared__ unsigned h[512];
    const int tid = threadIdx.x, b = blockIdx.x;
    const unsigned beg = bbase_s[b], end = bbase_s[b + 1];
    const int cnt = (int)(end - beg);
    if (tid < 512) h[tid] = 0;
    __syncthreads();
    for (int i = tid; i < cnt; i += 1024) atomicAdd(&h[outs[beg + i]], 1u);
    __syncthreads();
    const int n0 = b << BSH;
    const int nb = min(512, NN - n0);
    if (tid < nb) dno[n0 + tid] = rsqrtf(fmaxf((float)h[tid], 1.0f));
}

// ---------------- W[K,N] fp32 -> Wt[N,K] bf16 ----------------
__global__ __launch_bounds__(256)
void k_wt(const float* __restrict__ W, ushort* __restrict__ Wt, int K, int N) {
    int idx = blockIdx.x * 256 + threadIdx.x;
    if (idx >= K * N) return;
    int n = idx / K, k = idx - n * K;
    Wt[idx] = f2bf(W[(size_t)k * N + n]);
}

// ---------------- head weights: Wh[80][256] = [Wa^T; Wv^T; 0] bf16 ----------------
__global__ __launch_bounds__(256)
void k_wth(const float* __restrict__ Wa, const float* __restrict__ Wv,
           ushort* __restrict__ Wh) {
    int idx = blockIdx.x * 256 + threadIdx.x;
    if (idx >= 80 * HID) return;
    int n = idx / HID, k = idx - n * HID;
    float v = 0.f;
    if (n < ADIM) v = Wa[(size_t)k * ADIM + n];
    else if (n == ADIM) v = Wv[k];
    Wh[idx] = f2bf(v);
}

// ---------------- feat fp32 -> bf16 prescaled by dno[row] ----------------
__global__ __launch_bounds__(256)
void k_prescale_cvt(const float* __restrict__ X, const float* __restrict__ dno,
                    ushort* __restrict__ Y, int total4) {
    int idx = blockIdx.x * 256 + threadIdx.x;
    if (idx >= total4) return;
    int row = idx >> 5;
    float s = dno[row];
    float4 v = reinterpret_cast<const float4*>(X)[idx];
    ushort4 o;
    o.x = f2bf(v.x * s); o.y = f2bf(v.y * s);
    o.z = f2bf(v.z * s); o.w = f2bf(v.w * s);
    reinterpret_cast<ushort4*>(Y)[idx] = o;
}

// ---------------- pull SpMM over bf16 rows ----------------
template <int F>
__global__ __launch_bounds__(256)
void k_spmm_bf16(const int* __restrict__ row_ptr, const int* __restrict__ csr_src,
                 const ushort* __restrict__ X, const float* __restrict__ dni,
                 ushort* __restrict__ Y, int N) {
    const int node = blockIdx.x * 4 + (threadIdx.x >> 6);
    if (node >= N) return;
    const int lane = threadIdx.x & 63;
    const int beg = row_ptr[node];
    const int end = row_ptr[node + 1];
    float acc[4] = {0.f, 0.f, 0.f, 0.f};

    if (F == 256) {
        const ushort* Xl = X + lane * 4;
        int e = beg;
        for (; e + 1 < end; e += 2) {
            int s0 = csr_src[e];
            int s1 = csr_src[e + 1];
            ushort4 v0 = *reinterpret_cast<const ushort4*>(Xl + (size_t)s0 * 256);
            ushort4 v1 = *reinterpret_cast<const ushort4*>(Xl + (size_t)s1 * 256);
            acc[0] += bf2f(v0.x) + bf2f(v1.x);
            acc[1] += bf2f(v0.y) + bf2f(v1.y);
            acc[2] += bf2f(v0.z) + bf2f(v1.z);
            acc[3] += bf2f(v0.w) + bf2f(v1.w);
        }
        if (e < end) {
            int s0 = csr_src[e];
            ushort4 v0 = *reinterpret_cast<const ushort4*>(Xl + (size_t)s0 * 256);
            acc[0] += bf2f(v0.x); acc[1] += bf2f(v0.y);
            acc[2] += bf2f(v0.z); acc[3] += bf2f(v0.w);
        }
        float wi = dni[node];
        ushort4 o;
        o.x = f2bf(acc[0] * wi); o.y = f2bf(acc[1] * wi);
        o.z = f2bf(acc[2] * wi); o.w = f2bf(acc[3] * wi);
        *reinterpret_cast<ushort4*>(Y + (size_t)node * 256 + lane * 4) = o;
    } else {
        const int half = lane >> 5;
        const int l = lane & 31;
        const ushort* Xl = X + l * 4;
        for (int e = beg + half; e < end; e += 2) {
            int s = csr_src[e];
            ushort4 v = *reinterpret_cast<const ushort4*>(Xl + (size_t)s * 128);
            acc[0] += bf2f(v.x); acc[1] += bf2f(v.y);
            acc[2] += bf2f(v.z); acc[3] += bf2f(v.w);
        }
        acc[0] += __shfl_xor(acc[0], 32);
        acc[1] += __shfl_xor(acc[1], 32);
        acc[2] += __shfl_xor(acc[2], 32);
        acc[3] += __shfl_xor(acc[3], 32);
        if (half == 0) {
            float wi = dni[node];
            ushort4 o;
            o.x = f2bf(acc[0] * wi); o.y = f2bf(acc[1] * wi);
            o.z = f2bf(acc[2] * wi); o.w = f2bf(acc[3] * wi);
            *reinterpret_cast<ushort4*>(Y + (size_t)node * 128 + l * 4) = o;
        }
    }
}

// ---------------- MFMA GEMM 128x256 tile + fused BN column stats ----------------
// out bf16 [M,256] = A[M,K]bf16 @ Wt[256,K]^T + bias; stats += col sums/sumsq.
template <int K>
__global__ __launch_bounds__(256, 2)
void k_gemm_mfma(const ushort* __restrict__ A, const ushort* __restrict__ Wt,
                 const float* __restrict__ bias, ushort* __restrict__ outb,
                 float* __restrict__ stats, int M) {
    __shared__ ushort As[128][40];     // 32 k + pad
    __shared__ ushort Bs[256][40];
    __shared__ float sred[4][2][128];
    const int tid = threadIdx.x;
    const int w = tid >> 6;
    const int lane = tid & 63;
    const int wr = (w >> 1) * 64;      // wave row offset in tile
    const int wc = (w & 1) * 128;      // wave col offset
    const int row0 = blockIdx.x * 128;
    f32x4 acc[4][8] = {};

    const int frow = lane & 15;
    const int fk = (lane >> 4) * 8;

    for (int k0 = 0; k0 < K; k0 += 32) {
        #pragma unroll
        for (int h = 0; h < 2; ++h) {
            int slot = tid + 256 * h;          // 0..511
            int r = slot >> 2;
            int c = (slot & 3) * 8;
            int row = row0 + r;
            int4 v = make_int4(0, 0, 0, 0);
            if (row < M) v = *reinterpret_cast<const int4*>(A + (size_t)row * K + k0 + c);
            *reinterpret_cast<int4*>(&As[r][c]) = v;
        }
        #pragma unroll
        for (int h = 0; h < 4; ++h) {
            int slot = tid + 256 * h;          // 0..1023
            int n = slot >> 2;
            int c = (slot & 3) * 8;
            int4 v = *reinterpret_cast<const int4*>(Wt + (size_t)n * K + k0 + c);
            *reinterpret_cast<int4*>(&Bs[n][c]) = v;
        }
        __syncthreads();

        short8 afr[4], bfr[8];
        #pragma unroll
        for (int mi = 0; mi < 4; ++mi)
            afr[mi] = *reinterpret_cast<const short8*>(&As[wr + mi * 16 + frow][fk]);
        #pragma unroll
        for (int ni = 0; ni < 8; ++ni)
            bfr[ni] = *reinterpret_cast<const short8*>(&Bs[wc + ni * 16 + frow][fk]);
        #pragma unroll
        for (int mi = 0; mi < 4; ++mi)
            #pragma unroll
            for (int ni = 0; ni < 8; ++ni)
                acc[mi][ni] = __builtin_amdgcn_mfma_f32_16x16x32_bf16(afr[mi], bfr[ni], acc[mi][ni], 0, 0, 0);
        __syncthreads();
    }

    // epilogue: D col=lane&15, row=(lane>>4)*4+q
    const int ncol = lane & 15;
    const int rbase = (lane >> 4) * 4;
    #pragma unroll
    for (int ni = 0; ni < 8; ++ni) {
        int col = wc + ni * 16 + ncol;
        float b = bias[col];
        float s1 = 0.f, s2 = 0.f;
        #pragma unroll
        for (int mi = 0; mi < 4; ++mi) {
            #pragma unroll
            for (int q = 0; q < 4; ++q) {
                int row = row0 + wr + mi * 16 + rbase + q;
                if (row < M) {
                    float val = acc[mi][ni][q] + b;
                    outb[(size_t)row * HID + col] = f2bf(val);
                    s1 += val;
                    s2 += val * val;
                }
            }
        }
        s1 += __shfl_xor(s1, 16); s1 += __shfl_xor(s1, 32);
        s2 += __shfl_xor(s2, 16); s2 += __shfl_xor(s2, 32);
        if ((lane >> 4) == 0) {
            sred[w][0][ni * 16 + ncol] = s1;
            sred[w][1][ni * 16 + ncol] = s2;
        }
    }
    __syncthreads();
    // combine wave pairs: cols 0-127 from waves 0,2; cols 128-255 from waves 1,3
    {
        int c = tid;                 // 0..255
        int half = c >> 7, cl = c & 127;
        float v0 = sred[half][0][cl] + sred[half + 2][0][cl];
        float v1 = sred[half][1][cl] + sred[half + 2][1][cl];
        atomAdd(&stats[c], v0);
        atomAdd(&stats[HID + c], v1);
    }
}

// ---------------- BN + ReLU + dno-prescale: Gb bf16 -> Xb bf16 ----------------
__global__ __launch_bounds__(256)
void k_bn_relu_ps(const ushort* __restrict__ Gb, const float* __restrict__ stats,
                  const float* __restrict__ gamma, const float* __restrict__ beta,
                  const float* __restrict__ dno, ushort* __restrict__ Y, int total8) {
    int idx = blockIdx.x * 256 + threadIdx.x;
    if (idx >= total8) return;
    int row = idx >> 5;
    int c0 = (idx & 31) * 8;
    short8 v = *reinterpret_cast<const short8*>(Gb + (size_t)idx * 8);
    float s = dno[row];
    float inv_n = 1.0f / (float)NN;
    short8 o;
    #pragma unroll
    for (int j = 0; j < 8; ++j) {
        int c = c0 + j;
        float mean = stats[c] * inv_n;
        float var = stats[HID + c] * inv_n - mean * mean;
        float sc = gamma[c] * rsqrtf(var + BN_EPS);
        float sh = beta[c] - mean * sc;
        float x = bf2f((ushort)v[j]);
        float y = fmaf(x, sc, sh);
        y = y > 0.f ? y : 0.f;
        o[j] = (short)f2bf(y * s);
    }
    *reinterpret_cast<short8*>(Y + (size_t)idx * 8) = o;
}

// ---------------- fused BN2 + ReLU + dueling Q head (MFMA) ----------------
// Wh bf16 [80][256]: rows 0-63 = Wa^T, row 64 = Wv, rows 65-79 = 0.
__global__ __launch_bounds__(256)
void k_bn_qhead(const ushort* __restrict__ Gb, const float* __restrict__ stats,
                const float* __restrict__ gamma, const float* __restrict__ beta,
                const ushort* __restrict__ Wh, const float* __restrict__ ba,
                const float* __restrict__ bv, float* __restrict__ out, int M) {
    __shared__ ushort As[128][40];
    __shared__ ushort Bs[80][264];     // full K panel, pad 8
    __shared__ float sc_s[HID], sh_s[HID];
    const int tid = threadIdx.x;
    const int w = tid >> 6;
    const int lane = tid & 63;
    const int row0 = blockIdx.x * 128;
    const int frow = lane & 15;
    const int fk8 = (lane >> 4) * 8;

    // BN coefficients
    {
        float inv_n = 1.0f / (float)NN;
        float mean = stats[tid] * inv_n;
        float var = stats[HID + tid] * inv_n - mean * mean;
        float sc = gamma[tid] * rsqrtf(var + BN_EPS);
        sc_s[tid] = sc;
        sh_s[tid] = beta[tid] - mean * sc;
    }
    // stage Wh panel: 80*256 elems = 2560 int4 chunks, 10 per thread
    #pragma unroll
    for (int h = 0; h < 10; ++h) {
        int slot = tid + 256 * h;
        int n = slot >> 5;
        int c = (slot & 31) * 8;
        int4 v = *reinterpret_cast<const int4*>(Wh + (size_t)n * HID + c);
        *reinterpret_cast<int4*>(&Bs[n][c]) = v;
    }
    __syncthreads();

    f32x4 acc[2][5] = {};
    for (int k0 = 0; k0 < HID; k0 += 32) {
        // stage A: BN+ReLU(Gb[128][k0..k0+32]) -> bf16
        #pragma unroll
        for (int h = 0; h < 2; ++h) {
            int slot = tid + 256 * h;
            int r = slot >> 2;
            int c = (slot & 3) * 8;
            int row = row0 + r;
            short8 o = {};
            if (row < M) {
                short8 v = *reinterpret_cast<const short8*>(Gb + (size_t)row * HID + k0 + c);
                #pragma unroll
                for (int j = 0; j < 8; ++j) {
                    int k = k0 + c + j;
                    float y = fmaf(bf2f((ushort)v[j]), sc_s[k], sh_s[k]);
                    o[j] = (short)f2bf(y > 0.f ? y : 0.f);
                }
            }
            *reinterpret_cast<short8*>(&As[r][c]) = o;
        }
        __syncthreads();
        short8 afr[2], bfr[5];
        #pragma unroll
        for (int mi = 0; mi < 2; ++mi)
            afr[mi] = *reinterpret_cast<const short8*>(&As[w * 32 + mi * 16 + frow][fk8]);
        #pragma unroll
        for (int ni = 0; ni < 5; ++ni)
            bfr[ni] = *reinterpret_cast<const short8*>(&Bs[ni * 16 + frow][k0 + fk8]);
        #pragma unroll
        for (int mi = 0; mi < 2; ++mi)
            #pragma unroll
            for (int ni = 0; ni < 5; ++ni)
                acc[mi][ni] = __builtin_amdgcn_mfma_f32_16x16x32_bf16(afr[mi], bfr[ni], acc[mi][ni], 0, 0, 0);
        __syncthreads();
    }

    // epilogue: dueling combine
    const int ncol = lane & 15;
    const int gb = lane & 48;          // lane holding ncol==0 of this group
    const float bv0 = bv[0];
    float ba_l[4];
    #pragma unroll
    for (int ni = 0; ni < 4; ++ni) ba_l[ni] = ba[ni * 16 + ncol];
    #pragma unroll
    for (int mi = 0; mi < 2; ++mi) {
        #pragma unroll
        for (int q = 0; q < 4; ++q) {
            int row = row0 + w * 32 + mi * 16 + (lane >> 4) * 4 + q;
            float adv[4];
            float s = 0.f;
            #pragma unroll
            for (int ni = 0; ni < 4; ++ni) {
                adv[ni] = acc[mi][ni][q] + ba_l[ni];
                s += adv[ni];
            }
            s += __shfl_xor(s, 1); s += __shfl_xor(s, 2);
            s += __shfl_xor(s, 4); s += __shfl_xor(s, 8);
            float mean = s * (1.0f / ADIM);
            float val = acc[mi][4][q] + bv0;   // valid at ncol==0
            val = __shfl(val, gb);
            if (row < M) {
                #pragma unroll
                for (int ni = 0; ni < 4; ++ni)
                    out[(size_t)row * ADIM + ni * 16 + ncol] = val + adv[ni] - mean;
            }
        }
    }
}

extern "C" void kernel_launch(void* const* d_in, const int* in_sizes, int n_in,
                              void* d_out, int out_size, void* d_ws, size_t ws_size,
                              hipStream_t stream) {
    const float* feat = (const float*)d_in[0];
    const int* src = (const int*)d_in[1];
    const int* dst = (const int*)d_in[2];
    const float* W1 = (const float*)d_in[3];
    const float* b1 = (const float*)d_in[4];
    const float* g1 = (const float*)d_in[5];
    const float* be1 = (const float*)d_in[6];
    const float* W2 = (const float*)d_in[7];
    const float* b2 = (const float*)d_in[8];
    const float* g2 = (const float*)d_in[9];
    const float* be2 = (const float*)d_in[10];
    const float* Wa = (const float*)d_in[11];
    const float* ba = (const float*)d_in[12];
    const float* Wv = (const float*)d_in[13];
    const float* bv = (const float*)d_in[14];
    float* out = (float*)d_out;

    char* w = (char*)d_ws;
    unsigned* gh_d   = (unsigned*)w;  w += (size_t)NB * 16 * 4;
    unsigned* gh_s   = (unsigned*)w;  w += (size_t)NB * 16 * 4;
    float* stats     = (float*)w;     w += 1024 * 4;
    unsigned* gcur_d = (unsigned*)w;  w += (size_t)NB * 16 * 4;
    unsigned* gcur_s = (unsigned*)w;  w += (size_t)NB * 16 * 4;
    unsigned* bbase_d= (unsigned*)w;  w += (NB + 4) * 4;
    unsigned* bbase_s= (unsigned*)w;  w += (NB + 4) * 4;
    float* dn_out    = (float*)w;     w += (size_t)NN * 4;
    float* dn_in     = (float*)w;     w += (size_t)NN * 4;
    int* row_ptr     = (int*)w;       w += (size_t)(NN + 4) * 4;
    unsigned* outd   = (unsigned*)w;  w += (size_t)NE * 4;
    ushort* outs     = (ushort*)w;    w += (size_t)NE * 2;
    int* csr_src     = (int*)w;       w += (size_t)NE * 4;
    ushort* Wt1      = (ushort*)w;    w += (size_t)HID * SDIM * 2;
    ushort* Wt2      = (ushort*)w;    w += (size_t)HID * HID * 2;
    ushort* Whb      = (ushort*)w;    w += (size_t)80 * HID * 2;
    ushort* Xb       = (ushort*)w;    w += (size_t)NN * HID * 2;
    ushort* Ab       = (ushort*)w;    w += (size_t)NN * HID * 2;
    ushort* Gb       = (ushort*)w;    w += (size_t)NN * HID * 2;

    // zero bucket histograms + stats (contiguous)
    hipMemsetAsync(gh_d, 0, (size_t)2 * NB * 16 * 4 + 1024 * 4, stream);

    // CSR build via two-level counting sort
    k_hist<<<NAB, 1024, 0, stream>>>(src, dst, gh_d, gh_s, NE);
    k_scan_b<<<1, 256, 0, stream>>>(gh_d, gh_s, gcur_d, gcur_s, bbase_d, bbase_s, row_ptr);
    k_part<<<NAB, 1024, 0, stream>>>(src, dst, gcur_d, gcur_s, outd, outs, NE);
    k_csr<<<NB, 1024, 0, stream>>>(outd, bbase_d, row_ptr, csr_src, dn_in);
    k_degout<<<NB, 1024, 0, stream>>>(outs, bbase_s, dn_out);

    // weights
    k_wt<<<(SDIM * HID + 255) / 256, 256, 0, stream>>>(W1, Wt1, SDIM, HID);
    k_wt<<<(HID * HID + 255) / 256, 256, 0, stream>>>(W2, Wt2, HID, HID);
    k_wth<<<(80 * HID + 255) / 256, 256, 0, stream>>>(Wa, Wv, Whb);

    const int gblocks = (NN + 127) / 128;

    // layer 1
    {
        int t4 = NN * (SDIM / 4);
        k_prescale_cvt<<<(t4 + 255) / 256, 256, 0, stream>>>(feat, dn_out, Xb, t4);
        k_spmm_bf16<SDIM><<<(NN + 3) / 4, 256, 0, stream>>>(row_ptr, csr_src, Xb, dn_in, Ab, NN);
        k_gemm_mfma<SDIM><<<gblocks, 256, 0, stream>>>(Ab, Wt1, b1, Gb, stats, NN);
        int t8 = NN * (HID / 8);
        k_bn_relu_ps<<<(t8 + 255) / 256, 256, 0, stream>>>(Gb, stats, g1, be1, dn_out, Xb, t8);
    }

    // layer 2
    {
        k_spmm_bf16<HID><<<(NN + 3) / 4, 256, 0, stream>>>(row_ptr, csr_src, Xb, dn_in, Ab, NN);
        k_gemm_mfma<HID><<<gblocks, 256, 0, stream>>>(Ab, Wt2, b2, Gb, stats + 512, NN);
        k_bn_qhead<<<gblocks, 256, 0, stream>>>(Gb, stats + 512, g2, be2, Whb, ba, bv, out, NN);
    }
}